// Round 8
// baseline (360.602 us; speedup 1.0000x reference)
//
#include <hip/hip_runtime.h>
#include <hip/hip_bf16.h>

// B=4, T=128, N=512, D=32, CHEB_K=3, EMB=10, HEADS=2, TA_LAYERS=2, GCN_NUM=3,
// TCN_BLOCKS=3, KSIZE=3.  Inputs/outputs fp32; internal bf16 + MFMA.

typedef __attribute__((ext_vector_type(8))) short short8;
typedef __attribute__((ext_vector_type(4))) short short4v;
typedef __attribute__((ext_vector_type(4))) float float4v;

#define MFMA32(a, b, c) __builtin_amdgcn_mfma_f32_16x16x32_bf16((a), (b), (c), 0, 0, 0)
#if defined(__has_builtin)
#if __has_builtin(__builtin_amdgcn_mfma_f32_16x16x16_bf16)
#define MFMA16A(a, b, c) __builtin_amdgcn_mfma_f32_16x16x16_bf16((a), (b), (c), 0, 0, 0)
#endif
#endif
#ifndef MFMA16A
#define MFMA16A(a, b, c) __builtin_amdgcn_mfma_f32_16x16x16bf16_1k((a), (b), (c), 0, 0, 0)
#endif

#if defined(__has_builtin)
#if __has_builtin(__builtin_amdgcn_exp2f)
#define EXP2F(x) __builtin_amdgcn_exp2f(x)
#endif
#endif
#ifndef EXP2F
#define EXP2F(x) exp2f(x)
#endif

typedef const __attribute__((address_space(1))) unsigned int* gas_ptr;
typedef __attribute__((address_space(3))) unsigned int* las_ptr;
__device__ __forceinline__ void glds16(const void* g, void* l) {
  __builtin_amdgcn_global_load_lds((gas_ptr)g, (las_ptr)l, 16, 0, 0);
}

// packed fp32x2 -> bf16x2 (v_cvt_pk_bf16_f32 on gfx950), RNE
__device__ __forceinline__ unsigned int f2b2(float lo, float hi) {
  union { __hip_bfloat162 h; unsigned int u; } cv;
  cv.h = __float22bfloat162_rn(make_float2(lo, hi));
  return cv.u;
}
// single fp32 -> bf16 via cvt_pk (1 VALU op vs 4 for manual RNE)
__device__ __forceinline__ unsigned short f2b(float f) {
  return (unsigned short)f2b2(f, f);
}
__device__ __forceinline__ float b2f(unsigned short u) {
  return __uint_as_float(((unsigned int)u) << 16);
}
__device__ __forceinline__ ushort4 f2b4(float a, float b, float c, float d) {
  union { unsigned int u[2]; ushort4 s; } cv;
  cv.u[0] = f2b2(a, b);
  cv.u[1] = f2b2(c, d);
  return cv.s;
}

// ================= fused prep: all independent preprocessing ==============
__global__ void __launch_bounds__(256) prep_all(
    const float* __restrict__ adj, unsigned short* __restrict__ Sb,
    const float* __restrict__ emb, const float* __restrict__ gw,
    const float* __restrict__ gb, unsigned short* __restrict__ W8,
    float* __restrict__ biasn,
    const float* __restrict__ w1g, const float* __restrict__ w2g,
    unsigned short* __restrict__ Wt,
    const float* __restrict__ wqg, const float* __restrict__ wkg,
    const float* __restrict__ wvg, const float* __restrict__ wog,
    unsigned short* __restrict__ Wf,
    const float* __restrict__ x, unsigned short* __restrict__ H8,
    unsigned short* __restrict__ Hrm) {
  __shared__ unsigned short Asq[128 * 40];
  __shared__ unsigned short Bsq[128 * 40];
  int bid = blockIdx.x, tid = threadIdx.x;

  if (bid < 64) {
    int base = bid * 4096;
#pragma unroll
    for (int it = 0; it < 4; ++it) {
      int e = base + it * 1024 + tid * 4;
      float4 v = *(const float4*)&adj[e];
      union { unsigned int u[2]; ushort4 s; } pk;
      pk.u[0] = f2b2(v.x, v.y);
      pk.u[1] = f2b2(v.z, v.w);
      *(ushort4*)&Sb[e] = pk.s;
    }
    return;
  }
  if (bid < 80) {
    // ---- A^2 via MFMA: 128x128 tile, K=512 in 16 steps ----
    int tb = bid - 64;
    int mt = tb >> 2, jt = tb & 3;
    int m0 = mt * 128, j0 = jt * 128;
    int wave = tid >> 6, lane = tid & 63;
    int wm = wave >> 1, wj = wave & 1;
    int l15 = lane & 15, quad = lane >> 4;
    float4v acc[4][4];
#pragma unroll
    for (int a = 0; a < 4; ++a)
#pragma unroll
      for (int b = 0; b < 4; ++b) acc[a][b] = (float4v)0.f;
    for (int kt = 0; kt < 512; kt += 32) {
#pragma unroll
      for (int p = 0; p < 16; ++p) {
        int idx = p * 256 + tid;
        int m = idx >> 5, k = idx & 31;
        Asq[m * 40 + k] = f2b(adj[(m0 + m) * 512 + kt + k]);
      }
#pragma unroll
      for (int p = 0; p < 16; ++p) {
        int idx = p * 256 + tid;
        int k = idx >> 7, j = idx & 127;
        Bsq[j * 40 + k] = f2b(adj[(kt + k) * 512 + j0 + j]);
      }
      __syncthreads();
      short8 af[4], bfr[4];
#pragma unroll
      for (int mi = 0; mi < 4; ++mi)
        af[mi] = *(const short8*)&Asq[(wm * 64 + mi * 16 + l15) * 40 + quad * 8];
#pragma unroll
      for (int ji = 0; ji < 4; ++ji)
        bfr[ji] = *(const short8*)&Bsq[(wj * 64 + ji * 16 + l15) * 40 + quad * 8];
#pragma unroll
      for (int mi = 0; mi < 4; ++mi)
#pragma unroll
        for (int ji = 0; ji < 4; ++ji)
          acc[mi][ji] = MFMA32(af[mi], bfr[ji], acc[mi][ji]);
      __syncthreads();
    }
#pragma unroll
    for (int mi = 0; mi < 4; ++mi)
#pragma unroll
      for (int ji = 0; ji < 4; ++ji) {
        int j = j0 + wj * 64 + ji * 16 + l15;
#pragma unroll
        for (int r = 0; r < 4; ++r) {
          int m = m0 + wm * 64 + mi * 16 + quad * 4 + r;
          Sb[(512 + m) * 512 + j] =
              f2b(2.f * acc[mi][ji][r] - (m == j ? 1.f : 0.f));
        }
      }
    return;
  }
  if (bid < 1616) {
    int b2 = bid - 80;
    int i = b2 >> 9, n = b2 & 511;
    float ev[10];
#pragma unroll
    for (int e = 0; e < 10; ++e) ev[e] = emb[n * 10 + e];
    for (int idx = tid; idx < 3072; idx += 256) {
      int s = idx >> 10, c = (idx >> 5) & 31, o = idx & 31;
      float acc = 0.f;
#pragma unroll
      for (int e = 0; e < 10; ++e) acc += ev[e] * gw[(i * 10 + e) * 3072 + idx];
      W8[((i * 512 + n) * 3 + s) * 1024 + (c >> 3) * 256 + o * 8 + (c & 7)] =
          f2b(acc);
    }
    if (tid < 32) {
      float acc = 0.f;
#pragma unroll
      for (int e = 0; e < 10; ++e) acc += ev[e] * gb[(i * 10 + e) * 32 + tid];
      biasn[(i * 512 + n) * 32 + tid] = acc;
    }
    return;
  }
  if (bid < 1622) {
    int b2 = bid - 1616;
    int blk = b2 >> 1, conv = b2 & 1;
    const float* w = (conv ? w2g : w1g) + blk * 3072;
    for (int idx = tid; idx < 3072; idx += 256) {
      int kk = idx >> 10, rem = idx & 1023;
      int o = rem >> 5, c = rem & 31;
      Wt[b2 * 3072 + idx] = f2b(w[o * 96 + c * 3 + kk]);
    }
    return;
  }
  if (bid < 1654) {
    int idx = (bid - 1622) * 256 + tid;
    int L = idx >> 12;
    int mat = (idx >> 10) & 3;
    int nt = (idx >> 9) & 1;
    int lane = (idx >> 3) & 63;
    int j = idx & 7;
    int quad = lane >> 4, l15 = lane & 15;
    const float* base =
        (mat == 0 ? wqg : mat == 1 ? wkg : mat == 2 ? wvg : wog) + L * 1024;
    float v = base[(quad * 8 + j) * 32 + nt * 16 + l15];
    if (mat == 0) v *= 0.36067376022224085f;
    Wf[idx] = f2b(v);
    return;
  }
  {
    int b2 = bid - 1654;  // 512 = nblk(64) x part(8)
    int nblk = b2 >> 3, part = b2 & 7;
    for (int qq = tid; qq < 2048; qq += 256) {
      int q = part * 2048 + qq;
      int bt = q >> 5, c = q & 31;
      const float* xb = x + bt * 16384 + nblk * 256 + c;
      float f[8];
#pragma unroll
      for (int s = 0; s < 8; ++s) f[s] = xb[s * 32];
      union { unsigned int u[4]; uint4 v; } pk;
      pk.u[0] = f2b2(f[0], f[1]);
      pk.u[1] = f2b2(f[2], f[3]);
      pk.u[2] = f2b2(f[4], f[5]);
      pk.u[3] = f2b2(f[6], f[7]);
      *(uint4*)&H8[nblk * 131072 + q * 8] = pk.v;
    }
    for (int qq = tid; qq < 2048; qq += 256) {
      int q = part * 2048 + qq;
      int s = q >> 11, e0 = (q & 2047) * 8;
      int bt = e0 >> 5, c0 = e0 & 31;
      const float* xb = x + bt * 16384 + (nblk * 8 + s) * 32 + c0;
      float4 v0 = *(const float4*)&xb[0];
      float4 v1 = *(const float4*)&xb[4];
      union { unsigned int u[4]; uint4 v; } pk;
      pk.u[0] = f2b2(v0.x, v0.y);
      pk.u[1] = f2b2(v0.z, v0.w);
      pk.u[2] = f2b2(v1.x, v1.y);
      pk.u[3] = f2b2(v1.z, v1.w);
      *(uint4*)&Hrm[(nblk * 8 + s) * 16384 + e0] = pk.v;
    }
  }
}

// ---------------- GCN phase A: G = S @ H  (MFMA, bf16 out) --------------
// 256x128 tile, 512 threads / 8 waves, T4 counted-vmcnt pipeline.
__global__ void __launch_bounds__(512) gcn_phaseA(
    const unsigned short* __restrict__ Sb,
    const unsigned short* __restrict__ H8,
    unsigned short* __restrict__ G) {
  __shared__ unsigned short As[2][256 * 32];
  __shared__ unsigned short Bs[2][4096];
  int bid0 = blockIdx.x;  // 512
  int nb = (bid0 & 7) * 64 + (bid0 >> 3);  // XCD-contiguous, bijective
  int mt = nb & 3, jt = nb >> 2;
  int m0 = mt * 256, j0 = jt * 128;
  int tid = threadIdx.x;
  int wave = tid >> 6, lane = tid & 63;
  int wm = wave >> 1, wj = wave & 1;
  int l15 = lane & 15, quad = lane >> 4;
  float4v acc[4][4];
#pragma unroll
  for (int a = 0; a < 4; ++a)
#pragma unroll
    for (int b = 0; b < 4; ++b) acc[a][b] = (float4v)0.f;

  int qa0 = tid, qa1 = tid + 512;
  int ma0 = qa0 >> 2, ca0 = ((qa0 & 3) ^ ((qa0 >> 3) & 3)) * 8;
  int ma1 = qa1 >> 2, ca1 = ((qa1 & 3) ^ ((qa1 >> 3) & 3)) * 8;
  const unsigned short* sb0 = &Sb[(m0 + ma0) * 512 + ca0];
  const unsigned short* sb1 = &Sb[(m0 + ma1) * 512 + ca1];
  const unsigned short* hb0 = &H8[(tid >> 7) * 131072 + (j0 + (tid & 127)) * 8];

#define STAGE_A(buf, it2)                                   \
  {                                                         \
    int ncn = (it2) * 32;                                   \
    glds16(sb0 + ncn, &As[(buf)][qa0 * 8]);                 \
    glds16(sb1 + ncn, &As[(buf)][qa1 * 8]);                 \
    glds16(hb0 + (ncn >> 3) * 131072, &Bs[(buf)][tid * 8]); \
  }

  STAGE_A(0, 0);
  for (int it = 0; it < 16; ++it) {
    int cur = it & 1;
    if (it < 15) {
      STAGE_A(cur ^ 1, it + 1);
      asm volatile("s_waitcnt vmcnt(3)" ::: "memory");
    } else {
      asm volatile("s_waitcnt vmcnt(0)" ::: "memory");
    }
    __builtin_amdgcn_sched_barrier(0);
    __builtin_amdgcn_s_barrier();  // all waves' tile-cur loads landed
    short8 af[4], bfr[4];
#pragma unroll
    for (int mi = 0; mi < 4; ++mi) {
      int row = wm * 64 + mi * 16 + l15;
      int c8 = quad ^ ((row >> 1) & 3);  // read-side swizzle (same involution)
      af[mi] = *(const short8*)&As[cur][row * 32 + c8 * 8];
    }
#pragma unroll
    for (int ji = 0; ji < 4; ++ji)
      bfr[ji] =
          *(const short8*)&Bs[cur][quad * 1024 + (wj * 64 + ji * 16 + l15) * 8];
#pragma unroll
    for (int mi = 0; mi < 4; ++mi)
#pragma unroll
      for (int ji = 0; ji < 4; ++ji)
        acc[mi][ji] = MFMA32(af[mi], bfr[ji], acc[mi][ji]);
    __builtin_amdgcn_s_barrier();  // reads of buf[cur] done before overwrite
  }
#undef STAGE_A
#pragma unroll
  for (int mi = 0; mi < 4; ++mi)
#pragma unroll
    for (int ji = 0; ji < 4; ++ji) {
      int j = j0 + wj * 64 + ji * 16 + l15;
#pragma unroll
      for (int r = 0; r < 4; ++r) {
        int m = m0 + wm * 64 + mi * 16 + quad * 4 + r;
        G[m * 16384 + j] = f2b(acc[mi][ji][r]);
      }
    }
}

// ---------------- GCN phase B: per-node MFMA weight apply ----------------
// Hrm / tcnout outputs staged in LDS -> dense uint4 global stores (the
// scattered-2B-store fix); H8out's 8-node interleave stays inline scatter.
__global__ void __launch_bounds__(256) gcn_phaseB(
    const unsigned short* __restrict__ Hrm, const unsigned short* __restrict__ G,
    const unsigned short* __restrict__ W8, const float* __restrict__ biasn,
    unsigned short* __restrict__ H8out, unsigned short* __restrict__ Hrmout,
    unsigned short* __restrict__ tcnout) {
  __shared__ unsigned short stage[8192];  // 16 KB output staging
  int bid = blockIdx.x;  // 1024 = n(512) x bh(2)
  int n = bid >> 1, bh = bid & 1;
  int tid = threadIdx.x;
  int lane = tid & 63, wave = tid >> 6, l15 = lane & 15, quad = lane >> 4;
  short8 wb[3][2];
#pragma unroll
  for (int s = 0; s < 3; ++s)
#pragma unroll
    for (int nt = 0; nt < 2; ++nt)
      wb[s][nt] = *(const short8*)&W8[(n * 3 + s) * 1024 + quad * 256 +
                                      (nt * 16 + l15) * 8];
  float b0 = biasn[n * 32 + l15], b1 = biasn[n * 32 + 16 + l15];
  int n8base = (n >> 3) * 131072 + (n & 7);
#pragma unroll
  for (int mi = 0; mi < 4; ++mi) {
    int btl0 = wave * 64 + mi * 16;        // local bt within this bh half
    int bt0 = bh * 256 + btl0;
    int btl = bt0 + l15;
    short8 a0 = *(const short8*)&Hrm[n * 16384 + btl * 32 + quad * 8];
    short8 a1 = *(const short8*)&G[n * 16384 + btl * 32 + quad * 8];
    short8 a2 = *(const short8*)&G[(512 + n) * 16384 + btl * 32 + quad * 8];
    float4v acc0 = MFMA32(a0, wb[0][0], (float4v)0.f);
    acc0 = MFMA32(a1, wb[1][0], acc0);
    acc0 = MFMA32(a2, wb[2][0], acc0);
    float4v acc1 = MFMA32(a0, wb[0][1], (float4v)0.f);
    acc1 = MFMA32(a1, wb[1][1], acc1);
    acc1 = MFMA32(a2, wb[2][1], acc1);
#pragma unroll
    for (int r = 0; r < 4; ++r) {
      int bt = bt0 + quad * 4 + r;
      int bl = btl0 + quad * 4 + r;        // in [0,256)
      unsigned short v0 = f2b(acc0[r] + b0);
      unsigned short v1 = f2b(acc1[r] + b1);
      if (tcnout) {
        int o0 = l15, o1 = 16 + l15;
        stage[(bl >> 7) * 4096 + (o0 >> 3) * 1024 + (bl & 127) * 8 + (o0 & 7)] =
            v0;
        stage[(bl >> 7) * 4096 + (o1 >> 3) * 1024 + (bl & 127) * 8 + (o1 & 7)] =
            v1;
      } else {
        H8out[n8base + (bt * 32 + l15) * 8] = v0;
        H8out[n8base + (bt * 32 + 16 + l15) * 8] = v1;
        stage[bl * 32 + l15] = v0;
        stage[bl * 32 + 16 + l15] = v1;
      }
    }
  }
  __syncthreads();
  unsigned short* dst =
      (tcnout ? tcnout : Hrmout) + n * 16384 + bh * 8192;
#pragma unroll
  for (int it = 0; it < 4; ++it) {
    int i16 = it * 256 + tid;
    *(uint4*)&dst[i16 * 8] = *(const uint4*)&stage[i16 * 8];
  }
}

// ---------------- TCN: wave-per-(b,n), full MFMA, no barriers ----------
__global__ void __launch_bounds__(256) tcn_kernel(
    const unsigned short* __restrict__ Yin, unsigned short* __restrict__ yout,
    const unsigned short* __restrict__ Wt,
    const float* __restrict__ b1g, const float* __restrict__ b2g) {
  __shared__ unsigned short Y8[4][4352];
  __shared__ unsigned short O8[4][4352];
  int tid = threadIdx.x, wave = tid >> 6, lane = tid & 63;
  int l15 = lane & 15, quad = lane >> 4;
  int n = blockIdx.x, b = wave;
  unsigned short* y8 = &Y8[wave][0];
  unsigned short* o8 = &O8[wave][0];
  {
    int cg = lane >> 4, t = (lane >> 1) & 7, half = lane & 1;
    ushort4 z = {0, 0, 0, 0};
    *(ushort4*)&y8[(cg * 136 + t) * 8 + half * 4] = z;
    *(ushort4*)&o8[(cg * 136 + t) * 8 + half * 4] = z;
  }
  const unsigned short* src = Yin + n * 16384 + b * 4096;
#pragma unroll
  for (int p = 0; p < 8; ++p) {
    int e = p * 64 + lane;
    int cg = e >> 7, t = e & 127;
    *(uint4*)&y8[(cg * 136 + t + 8) * 8] = *(const uint4*)&src[e * 8];
  }
  for (int blk = 0; blk < 3; ++blk) {
    int dil = 1 << blk;
    for (int conv = 0; conv < 2; ++conv) {
      const unsigned short* wbase = Wt + ((blk * 2 + conv) * 3) * 1024;
      short8 af[2][3];
#pragma unroll
      for (int mt = 0; mt < 2; ++mt)
#pragma unroll
        for (int kk = 0; kk < 3; ++kk)
          af[mt][kk] = *(const short8*)&wbase[kk * 1024 +
                                              (mt * 16 + l15) * 32 + quad * 8];
      const float* bias = (conv ? b2g : b1g) + blk * 32;
      float4 bs0 = *(const float4*)&bias[quad * 4];
      float4 bs1 = *(const float4*)&bias[16 + quad * 4];
      float bb0[4] = {bs0.x, bs0.y, bs0.z, bs0.w};
      float bb1[4] = {bs1.x, bs1.y, bs1.z, bs1.w};
      const unsigned short* rbuf = conv ? o8 : y8;
#pragma unroll 2
      for (int nt = 0; nt < 8; ++nt) {
        float4v acc0 = (float4v)0.f, acc1 = (float4v)0.f;
#pragma unroll
        for (int kk = 0; kk < 3; ++kk) {
          int tb = nt * 16 + l15 + 8 - (2 - kk) * dil;
          short8 bf = *(const short8*)&rbuf[(quad * 136 + tb) * 8];
          acc0 = MFMA32(af[0][kk], bf, acc0);
          acc1 = MFMA32(af[1][kk], bf, acc1);
        }
        int t8 = nt * 16 + l15 + 8;
        int og0 = (quad >> 1), ci0 = (quad & 1) * 4;
        if (conv == 0) {
          ushort4 w0 = f2b4(fmaxf(acc0[0] + bb0[0], 0.f),
                            fmaxf(acc0[1] + bb0[1], 0.f),
                            fmaxf(acc0[2] + bb0[2], 0.f),
                            fmaxf(acc0[3] + bb0[3], 0.f));
          ushort4 w1 = f2b4(fmaxf(acc1[0] + bb1[0], 0.f),
                            fmaxf(acc1[1] + bb1[1], 0.f),
                            fmaxf(acc1[2] + bb1[2], 0.f),
                            fmaxf(acc1[3] + bb1[3], 0.f));
          *(ushort4*)&o8[((og0)*136 + t8) * 8 + ci0] = w0;
          *(ushort4*)&o8[((2 + og0) * 136 + t8) * 8 + ci0] = w1;
        } else {
          ushort4 y0 = *(const ushort4*)&y8[((og0)*136 + t8) * 8 + ci0];
          ushort4 y1 = *(const ushort4*)&y8[((2 + og0) * 136 + t8) * 8 + ci0];
          ushort4 w0 = f2b4(
              fmaxf(fmaxf(acc0[0] + bb0[0], 0.f) + b2f(y0.x), 0.f),
              fmaxf(fmaxf(acc0[1] + bb0[1], 0.f) + b2f(y0.y), 0.f),
              fmaxf(fmaxf(acc0[2] + bb0[2], 0.f) + b2f(y0.z), 0.f),
              fmaxf(fmaxf(acc0[3] + bb0[3], 0.f) + b2f(y0.w), 0.f));
          ushort4 w1 = f2b4(
              fmaxf(fmaxf(acc1[0] + bb1[0], 0.f) + b2f(y1.x), 0.f),
              fmaxf(fmaxf(acc1[1] + bb1[1], 0.f) + b2f(y1.y), 0.f),
              fmaxf(fmaxf(acc1[2] + bb1[2], 0.f) + b2f(y1.z), 0.f),
              fmaxf(fmaxf(acc1[3] + bb1[3], 0.f) + b2f(y1.w), 0.f));
          *(ushort4*)&y8[((og0)*136 + t8) * 8 + ci0] = w0;
          *(ushort4*)&y8[((2 + og0) * 136 + t8) * 8 + ci0] = w1;
        }
      }
    }
  }
  unsigned short* dst = yout + n * 16384 + b * 4096;
#pragma unroll
  for (int p = 0; p < 8; ++p) {
    int e = p * 64 + lane;
    int og = e >> 7, t = e & 127;
    *(uint4*)&dst[t * 32 + og * 8] = *(const uint4*)&y8[(og * 136 + t + 8) * 8];
  }
}

// ---------------- attention: 512 threads, 1 q-tile per wave --------------
// Max-subtracted softmax (RESTORED after R7 NaN: layer-0 input is TCN
// output, unbounded -- exp2 overflow without the max shift). LN via E[x^2].
__global__ void __launch_bounds__(512) attn_kernel(
    const unsigned short* __restrict__ yin,  // bf16 [n][b][t*32+d]
    float* __restrict__ outp,
    const unsigned short* __restrict__ Wf,   // precomputed bf16 frags
    const float* __restrict__ gg, const float* __restrict__ bgb) {
  __shared__ unsigned short hfrag[4096];     // h in A32-frag layout (+residual)
  __shared__ unsigned short KbOb[5120];      // Kb[128][36] / Ob[128][40] aliased
  __shared__ unsigned short QT[32 * 136];    // Q^T [d][t], pad 136
  __shared__ unsigned short VT[32 * 136];    // V^T [d][kt], pad 136
  int bn = blockIdx.x, tid = threadIdx.x;
  int b = bn >> 9, n = bn & 511;
  int lane = tid & 63, wave = tid >> 6;     // wave = q-tile (0..7)
  int l15 = lane & 15, quad = lane >> 4;
  int mtq = wave;

  {
    int q = tid;
    int t = ((q >> 6) << 4) | (q & 15);
    int cb = (q >> 4) & 3;
    glds16(&yin[n * 16384 + b * 4096 + (t * 4 + cb) * 8], &hfrag[q * 8]);
  }

  for (int L = 0; L < 2; ++L) {
    short8 wf[4][2];
#pragma unroll
    for (int mat = 0; mat < 4; ++mat)
#pragma unroll
      for (int nt = 0; nt < 2; ++nt)
        wf[mat][nt] =
            *(const short8*)&Wf[(((L * 4 + mat) * 2 + nt) * 64 + lane) * 8];
    __syncthreads();  // L0: hfrag staged (vmcnt drain); L1: prev reads done
    // ---- projections; write K row-major, Q^T/V^T transposed (b64) ----
    {
      short8 af = *(const short8*)&hfrag[(mtq * 4 + quad) * 128 + l15 * 8];
      int tbase = mtq * 16 + quad * 4;
#pragma unroll
      for (int nt = 0; nt < 2; ++nt) {
        float4v qa = MFMA32(af, wf[0][nt], (float4v)0.f);
        float4v ka = MFMA32(af, wf[1][nt], (float4v)0.f);
        float4v va = MFMA32(af, wf[2][nt], (float4v)0.f);
        int d = nt * 16 + l15;
#pragma unroll
        for (int r = 0; r < 4; ++r) KbOb[(tbase + r) * 36 + d] = f2b(ka[r]);
        *(ushort4*)&QT[d * 136 + tbase] = f2b4(qa[0], qa[1], qa[2], qa[3]);
        *(ushort4*)&VT[d * 136 + tbase] = f2b4(va[0], va[1], va[2], va[3]);
      }
    }
    __syncthreads();  // frags ready
    // ---- scores (S^T = K @ Q^T), softmax, PV ----
    float4v oaccT[2];
#pragma unroll
    for (int hh = 0; hh < 2; ++hh) oaccT[hh] = (float4v)0.f;
    for (int hh = 0; hh < 2; ++hh) {
      short4v qb;
#pragma unroll
      for (int jj = 0; jj < 4; ++jj)
        qb[jj] = (short)QT[(hh * 16 + quad * 4 + jj) * 136 + mtq * 16 + l15];
      float4v sacc[8];
#pragma unroll
      for (int st = 0; st < 8; ++st) {
        short4v ka = *(const short4v*)&KbOb[(st * 16 + l15) * 36 + hh * 16 +
                                            quad * 4];
        sacc[st] = MFMA16A(ka, qb, (float4v)0.f);
      }
      // tree max (v_max3-friendly, short dep chain)
      float tmx[8];
#pragma unroll
      for (int st = 0; st < 8; ++st)
        tmx[st] = fmaxf(fmaxf(sacc[st][0], sacc[st][1]),
                        fmaxf(sacc[st][2], sacc[st][3]));
      float mx = fmaxf(fmaxf(fmaxf(tmx[0], tmx[1]), fmaxf(tmx[2], tmx[3])),
                       fmaxf(fmaxf(tmx[4], tmx[5]), fmaxf(tmx[6], tmx[7])));
      mx = fmaxf(mx, __shfl_xor(mx, 16));
      mx = fmaxf(mx, __shfl_xor(mx, 32));
      float ps[8];
#pragma unroll
      for (int st = 0; st < 8; ++st) {
#pragma unroll
        for (int r = 0; r < 4; ++r) sacc[st][r] = EXP2F(sacc[st][r] - mx);
        ps[st] = (sacc[st][0] + sacc[st][1]) + (sacc[st][2] + sacc[st][3]);
      }
      float sum = ((ps[0] + ps[1]) + (ps[2] + ps[3])) +
                  ((ps[4] + ps[5]) + (ps[6] + ps[7]));
      sum += __shfl_xor(sum, 16);
      sum += __shfl_xor(sum, 32);
      float inv = 1.f / sum;
      // P stored unnormalized; 1/sum folded into O accumulator after PV
#pragma unroll
      for (int st = 0; st < 8; ++st) {
        union { unsigned int u[2]; short4v s; } pv;
        pv.u[0] = f2b2(sacc[st][0], sacc[st][1]);
        pv.u[1] = f2b2(sacc[st][2], sacc[st][3]);
        short4v va = *(const short4v*)&VT[(hh * 16 + l15) * 136 + st * 16 +
                                          quad * 4];
        oaccT[hh] = MFMA16A(va, pv.s, oaccT[hh]);
      }
#pragma unroll
      for (int r = 0; r < 4; ++r) oaccT[hh][r] *= inv;
    }
    __syncthreads();  // all Kb reads done before Ob overwrites the buffer
    // ---- O^T C-frag -> O row-major (b64, wave-local rows) ----
#pragma unroll
    for (int hh = 0; hh < 2; ++hh)
      *(ushort4*)&KbOb[(mtq * 16 + l15) * 40 + hh * 16 + quad * 4] =
          f2b4(oaccT[hh][0], oaccT[hh][1], oaccT[hh][2], oaccT[hh][3]);
    // ---- output projection + residual + layernorm (E[x^2] form) ----
    float gam0 = gg[L * 32 + l15], bet0 = bgb[L * 32 + l15];
    float gam1 = gg[L * 32 + 16 + l15], bet1 = bgb[L * 32 + 16 + l15];
    {
      short8 ofa = *(const short8*)&KbOb[(mtq * 16 + l15) * 40 + quad * 8];
      float4v racc0 = MFMA32(ofa, wf[3][0], (float4v)0.f);
      float4v racc1 = MFMA32(ofa, wf[3][1], (float4v)0.f);
      int hi0 = (mtq * 4 + (l15 >> 3)) * 128 + (l15 & 7);
      int hi1 = (mtq * 4 + 2 + (l15 >> 3)) * 128 + (l15 & 7);
#pragma unroll
      for (int r = 0; r < 4; ++r) {
        int t = mtq * 16 + quad * 4 + r;
        int ro = (quad * 4 + r) * 8;
        float v0 = racc0[r] + b2f(hfrag[hi0 + ro]);
        float v1 = racc1[r] + b2f(hfrag[hi1 + ro]);
        float s = v0 + v1;
        float q2 = v0 * v0 + v1 * v1;
        for (int m = 1; m < 16; m <<= 1) {
          s += __shfl_xor(s, m);
          q2 += __shfl_xor(q2, m);
        }
        float mu = s * 0.03125f;
        float var = q2 * 0.03125f - mu * mu;
        float rs = rsqrtf(var + 1e-5f);
        float y0 = (v0 - mu) * rs * gam0 + bet0;
        float y1 = (v1 - mu) * rs * gam1 + bet1;
        if (L == 0) {
          hfrag[hi0 + ro] = f2b(y0);  // wave-local rows; no barrier needed
          hfrag[hi1 + ro] = f2b(y1);
        } else {
          outp[((b * 128 + t) * 512 + n) * 32 + l15] = y0;
          outp[((b * 128 + t) * 512 + n) * 32 + 16 + l15] = y1;
        }
      }
    }
  }
}

extern "C" void kernel_launch(void* const* d_in, const int* in_sizes, int n_in,
                              void* d_out, int out_size, void* d_ws, size_t ws_size,
                              hipStream_t stream) {
  const float* x    = (const float*)d_in[0];
  const float* emb  = (const float*)d_in[2];
  const float* adj  = (const float*)d_in[3];
  const float* gw   = (const float*)d_in[4];
  const float* gb   = (const float*)d_in[5];
  const float* tw1  = (const float*)d_in[6];
  const float* tb1  = (const float*)d_in[7];
  const float* tw2  = (const float*)d_in[8];
  const float* tb2  = (const float*)d_in[9];
  const float* wq   = (const float*)d_in[10];
  const float* wk   = (const float*)d_in[11];
  const float* wv   = (const float*)d_in[12];
  const float* wo   = (const float*)d_in[13];
  const float* tg   = (const float*)d_in[14];
  const float* tbb  = (const float*)d_in[15];
  float* outp = (float*)d_out;

  char* p = (char*)d_ws;
  unsigned short* Sb  = (unsigned short*)p; p += 1048576;
  unsigned short* W8  = (unsigned short*)p; p += 9437184;
  float* biasn        = (float*)p;          p += 196608;
  unsigned short* G   = (unsigned short*)p; p += 33554432;
  unsigned short* H8a = (unsigned short*)p; p += 16777216;
  unsigned short* H8b = (unsigned short*)p; p += 16777216;
  unsigned short* Hra = (unsigned short*)p; p += 16777216;
  unsigned short* Hrb = (unsigned short*)p; p += 16777216;
  unsigned short* Wt  = (unsigned short*)p; p += 36864;
  unsigned short* Wf  = (unsigned short*)p; p += 16384;  // ~111.4 MB total

  prep_all<<<dim3(2166), dim3(256), 0, stream>>>(
      adj, Sb, emb, gw, gb, W8, biasn, tw1, tw2, Wt, wq, wk, wv, wo, Wf,
      x, H8a, Hra);

  gcn_phaseA<<<dim3(512), dim3(512), 0, stream>>>(Sb, H8a, G);
  gcn_phaseB<<<dim3(1024), dim3(256), 0, stream>>>(
      Hra, G, W8, biasn, H8b, Hrb, (unsigned short*)nullptr);
  gcn_phaseA<<<dim3(512), dim3(512), 0, stream>>>(Sb, H8b, G);
  gcn_phaseB<<<dim3(1024), dim3(256), 0, stream>>>(
      Hrb, G, W8 + 1572864, biasn + 16384, H8a, Hra, (unsigned short*)nullptr);
  gcn_phaseA<<<dim3(512), dim3(512), 0, stream>>>(Sb, H8a, G);
  gcn_phaseB<<<dim3(1024), dim3(256), 0, stream>>>(
      Hra, G, W8 + 3145728, biasn + 32768, (unsigned short*)nullptr,
      (unsigned short*)nullptr, H8b);

  tcn_kernel<<<dim3(512), dim3(256), 0, stream>>>(H8b, H8a, Wt, tb1, tb2);
  attn_kernel<<<dim3(2048), dim3(512), 0, stream>>>(H8a, outp, Wf, tg, tbb);
}

// Round 9
// 339.270 us; speedup vs baseline: 1.0629x; 1.0629x over previous
//
#include <hip/hip_runtime.h>
#include <hip/hip_bf16.h>

// B=4, T=128, N=512, D=32, CHEB_K=3, EMB=10, HEADS=2, TA_LAYERS=2, GCN_NUM=3,
// TCN_BLOCKS=3, KSIZE=3.  Inputs/outputs fp32; internal bf16 + MFMA.

typedef __attribute__((ext_vector_type(8))) short short8;
typedef __attribute__((ext_vector_type(4))) short short4v;
typedef __attribute__((ext_vector_type(4))) float float4v;

#define MFMA32(a, b, c) __builtin_amdgcn_mfma_f32_16x16x32_bf16((a), (b), (c), 0, 0, 0)
#if defined(__has_builtin)
#if __has_builtin(__builtin_amdgcn_mfma_f32_16x16x16_bf16)
#define MFMA16A(a, b, c) __builtin_amdgcn_mfma_f32_16x16x16_bf16((a), (b), (c), 0, 0, 0)
#endif
#endif
#ifndef MFMA16A
#define MFMA16A(a, b, c) __builtin_amdgcn_mfma_f32_16x16x16bf16_1k((a), (b), (c), 0, 0, 0)
#endif

#if defined(__has_builtin)
#if __has_builtin(__builtin_amdgcn_exp2f)
#define EXP2F(x) __builtin_amdgcn_exp2f(x)
#endif
#endif
#ifndef EXP2F
#define EXP2F(x) exp2f(x)
#endif

typedef const __attribute__((address_space(1))) unsigned int* gas_ptr;
typedef __attribute__((address_space(3))) unsigned int* las_ptr;
__device__ __forceinline__ void glds16(const void* g, void* l) {
  __builtin_amdgcn_global_load_lds((gas_ptr)g, (las_ptr)l, 16, 0, 0);
}

// packed fp32x2 -> bf16x2 (v_cvt_pk_bf16_f32 on gfx950), RNE
__device__ __forceinline__ unsigned int f2b2(float lo, float hi) {
  union { __hip_bfloat162 h; unsigned int u; } cv;
  cv.h = __float22bfloat162_rn(make_float2(lo, hi));
  return cv.u;
}
// single fp32 -> bf16 via cvt_pk (1 VALU op vs 4 for manual RNE)
__device__ __forceinline__ unsigned short f2b(float f) {
  return (unsigned short)f2b2(f, f);
}
__device__ __forceinline__ float b2f(unsigned short u) {
  return __uint_as_float(((unsigned int)u) << 16);
}
__device__ __forceinline__ ushort4 f2b4(float a, float b, float c, float d) {
  union { unsigned int u[2]; ushort4 s; } cv;
  cv.u[0] = f2b2(a, b);
  cv.u[1] = f2b2(c, d);
  return cv.s;
}

// ================= fused prep: all independent preprocessing ==============
__global__ void __launch_bounds__(256) prep_all(
    const float* __restrict__ adj, unsigned short* __restrict__ Sb,
    const float* __restrict__ emb, const float* __restrict__ gw,
    const float* __restrict__ gb, unsigned short* __restrict__ W8,
    float* __restrict__ biasn,
    const float* __restrict__ w1g, const float* __restrict__ w2g,
    unsigned short* __restrict__ Wt,
    const float* __restrict__ wqg, const float* __restrict__ wkg,
    const float* __restrict__ wvg, const float* __restrict__ wog,
    unsigned short* __restrict__ Wf,
    const float* __restrict__ x, unsigned short* __restrict__ H8,
    unsigned short* __restrict__ Hrm) {
  __shared__ unsigned short Asq[128 * 40];
  __shared__ unsigned short Bsq[128 * 40];
  int bid = blockIdx.x, tid = threadIdx.x;

  if (bid < 64) {
    int base = bid * 4096;
#pragma unroll
    for (int it = 0; it < 4; ++it) {
      int e = base + it * 1024 + tid * 4;
      float4 v = *(const float4*)&adj[e];
      union { unsigned int u[2]; ushort4 s; } pk;
      pk.u[0] = f2b2(v.x, v.y);
      pk.u[1] = f2b2(v.z, v.w);
      *(ushort4*)&Sb[e] = pk.s;
    }
    return;
  }
  if (bid < 80) {
    // ---- A^2 via MFMA: 128x128 tile, K=512 in 16 steps ----
    int tb = bid - 64;
    int mt = tb >> 2, jt = tb & 3;
    int m0 = mt * 128, j0 = jt * 128;
    int wave = tid >> 6, lane = tid & 63;
    int wm = wave >> 1, wj = wave & 1;
    int l15 = lane & 15, quad = lane >> 4;
    float4v acc[4][4];
#pragma unroll
    for (int a = 0; a < 4; ++a)
#pragma unroll
      for (int b = 0; b < 4; ++b) acc[a][b] = (float4v)0.f;
    for (int kt = 0; kt < 512; kt += 32) {
#pragma unroll
      for (int p = 0; p < 16; ++p) {
        int idx = p * 256 + tid;
        int m = idx >> 5, k = idx & 31;
        Asq[m * 40 + k] = f2b(adj[(m0 + m) * 512 + kt + k]);
      }
#pragma unroll
      for (int p = 0; p < 16; ++p) {
        int idx = p * 256 + tid;
        int k = idx >> 7, j = idx & 127;
        Bsq[j * 40 + k] = f2b(adj[(kt + k) * 512 + j0 + j]);
      }
      __syncthreads();
      short8 af[4], bfr[4];
#pragma unroll
      for (int mi = 0; mi < 4; ++mi)
        af[mi] = *(const short8*)&Asq[(wm * 64 + mi * 16 + l15) * 40 + quad * 8];
#pragma unroll
      for (int ji = 0; ji < 4; ++ji)
        bfr[ji] = *(const short8*)&Bsq[(wj * 64 + ji * 16 + l15) * 40 + quad * 8];
#pragma unroll
      for (int mi = 0; mi < 4; ++mi)
#pragma unroll
        for (int ji = 0; ji < 4; ++ji)
          acc[mi][ji] = MFMA32(af[mi], bfr[ji], acc[mi][ji]);
      __syncthreads();
    }
#pragma unroll
    for (int mi = 0; mi < 4; ++mi)
#pragma unroll
      for (int ji = 0; ji < 4; ++ji) {
        int j = j0 + wj * 64 + ji * 16 + l15;
#pragma unroll
        for (int r = 0; r < 4; ++r) {
          int m = m0 + wm * 64 + mi * 16 + quad * 4 + r;
          Sb[(512 + m) * 512 + j] =
              f2b(2.f * acc[mi][ji][r] - (m == j ? 1.f : 0.f));
        }
      }
    return;
  }
  if (bid < 1616) {
    int b2 = bid - 80;
    int i = b2 >> 9, n = b2 & 511;
    float ev[10];
#pragma unroll
    for (int e = 0; e < 10; ++e) ev[e] = emb[n * 10 + e];
    for (int idx = tid; idx < 3072; idx += 256) {
      int s = idx >> 10, c = (idx >> 5) & 31, o = idx & 31;
      float acc = 0.f;
#pragma unroll
      for (int e = 0; e < 10; ++e) acc += ev[e] * gw[(i * 10 + e) * 3072 + idx];
      W8[((i * 512 + n) * 3 + s) * 1024 + (c >> 3) * 256 + o * 8 + (c & 7)] =
          f2b(acc);
    }
    if (tid < 32) {
      float acc = 0.f;
#pragma unroll
      for (int e = 0; e < 10; ++e) acc += ev[e] * gb[(i * 10 + e) * 32 + tid];
      biasn[(i * 512 + n) * 32 + tid] = acc;
    }
    return;
  }
  if (bid < 1622) {
    int b2 = bid - 1616;
    int blk = b2 >> 1, conv = b2 & 1;
    const float* w = (conv ? w2g : w1g) + blk * 3072;
    for (int idx = tid; idx < 3072; idx += 256) {
      int kk = idx >> 10, rem = idx & 1023;
      int o = rem >> 5, c = rem & 31;
      Wt[b2 * 3072 + idx] = f2b(w[o * 96 + c * 3 + kk]);
    }
    return;
  }
  if (bid < 1654) {
    int idx = (bid - 1622) * 256 + tid;
    int L = idx >> 12;
    int mat = (idx >> 10) & 3;
    int nt = (idx >> 9) & 1;
    int lane = (idx >> 3) & 63;
    int j = idx & 7;
    int quad = lane >> 4, l15 = lane & 15;
    const float* base =
        (mat == 0 ? wqg : mat == 1 ? wkg : mat == 2 ? wvg : wog) + L * 1024;
    float v = base[(quad * 8 + j) * 32 + nt * 16 + l15];
    if (mat == 0) v *= 0.36067376022224085f;
    Wf[idx] = f2b(v);
    return;
  }
  {
    int b2 = bid - 1654;  // 512 = nblk(64) x part(8)
    int nblk = b2 >> 3, part = b2 & 7;
    for (int qq = tid; qq < 2048; qq += 256) {
      int q = part * 2048 + qq;
      int bt = q >> 5, c = q & 31;
      const float* xb = x + bt * 16384 + nblk * 256 + c;
      float f[8];
#pragma unroll
      for (int s = 0; s < 8; ++s) f[s] = xb[s * 32];
      union { unsigned int u[4]; uint4 v; } pk;
      pk.u[0] = f2b2(f[0], f[1]);
      pk.u[1] = f2b2(f[2], f[3]);
      pk.u[2] = f2b2(f[4], f[5]);
      pk.u[3] = f2b2(f[6], f[7]);
      *(uint4*)&H8[nblk * 131072 + q * 8] = pk.v;
    }
    for (int qq = tid; qq < 2048; qq += 256) {
      int q = part * 2048 + qq;
      int s = q >> 11, e0 = (q & 2047) * 8;
      int bt = e0 >> 5, c0 = e0 & 31;
      const float* xb = x + bt * 16384 + (nblk * 8 + s) * 32 + c0;
      float4 v0 = *(const float4*)&xb[0];
      float4 v1 = *(const float4*)&xb[4];
      union { unsigned int u[4]; uint4 v; } pk;
      pk.u[0] = f2b2(v0.x, v0.y);
      pk.u[1] = f2b2(v0.z, v0.w);
      pk.u[2] = f2b2(v1.x, v1.y);
      pk.u[3] = f2b2(v1.z, v1.w);
      *(uint4*)&Hrm[(nblk * 8 + s) * 16384 + e0] = pk.v;
    }
  }
}

// ---------------- GCN phase A: G = S @ H  (MFMA, bf16 out) --------------
// 256x128 tile, 512 threads / 8 waves, T4 counted-vmcnt pipeline.
__global__ void __launch_bounds__(512) gcn_phaseA(
    const unsigned short* __restrict__ Sb,
    const unsigned short* __restrict__ H8,
    unsigned short* __restrict__ G) {
  __shared__ unsigned short As[2][256 * 32];
  __shared__ unsigned short Bs[2][4096];
  int bid0 = blockIdx.x;  // 512
  int nb = (bid0 & 7) * 64 + (bid0 >> 3);  // XCD-contiguous, bijective
  int mt = nb & 3, jt = nb >> 2;
  int m0 = mt * 256, j0 = jt * 128;
  int tid = threadIdx.x;
  int wave = tid >> 6, lane = tid & 63;
  int wm = wave >> 1, wj = wave & 1;
  int l15 = lane & 15, quad = lane >> 4;
  float4v acc[4][4];
#pragma unroll
  for (int a = 0; a < 4; ++a)
#pragma unroll
    for (int b = 0; b < 4; ++b) acc[a][b] = (float4v)0.f;

  int qa0 = tid, qa1 = tid + 512;
  int ma0 = qa0 >> 2, ca0 = ((qa0 & 3) ^ ((qa0 >> 3) & 3)) * 8;
  int ma1 = qa1 >> 2, ca1 = ((qa1 & 3) ^ ((qa1 >> 3) & 3)) * 8;
  const unsigned short* sb0 = &Sb[(m0 + ma0) * 512 + ca0];
  const unsigned short* sb1 = &Sb[(m0 + ma1) * 512 + ca1];
  const unsigned short* hb0 = &H8[(tid >> 7) * 131072 + (j0 + (tid & 127)) * 8];

#define STAGE_A(buf, it2)                                   \
  {                                                         \
    int ncn = (it2) * 32;                                   \
    glds16(sb0 + ncn, &As[(buf)][qa0 * 8]);                 \
    glds16(sb1 + ncn, &As[(buf)][qa1 * 8]);                 \
    glds16(hb0 + (ncn >> 3) * 131072, &Bs[(buf)][tid * 8]); \
  }

  STAGE_A(0, 0);
  for (int it = 0; it < 16; ++it) {
    int cur = it & 1;
    if (it < 15) {
      STAGE_A(cur ^ 1, it + 1);
      asm volatile("s_waitcnt vmcnt(3)" ::: "memory");
    } else {
      asm volatile("s_waitcnt vmcnt(0)" ::: "memory");
    }
    __builtin_amdgcn_sched_barrier(0);
    __builtin_amdgcn_s_barrier();  // all waves' tile-cur loads landed
    short8 af[4], bfr[4];
#pragma unroll
    for (int mi = 0; mi < 4; ++mi) {
      int row = wm * 64 + mi * 16 + l15;
      int c8 = quad ^ ((row >> 1) & 3);  // read-side swizzle (same involution)
      af[mi] = *(const short8*)&As[cur][row * 32 + c8 * 8];
    }
#pragma unroll
    for (int ji = 0; ji < 4; ++ji)
      bfr[ji] =
          *(const short8*)&Bs[cur][quad * 1024 + (wj * 64 + ji * 16 + l15) * 8];
#pragma unroll
    for (int mi = 0; mi < 4; ++mi)
#pragma unroll
      for (int ji = 0; ji < 4; ++ji)
        acc[mi][ji] = MFMA32(af[mi], bfr[ji], acc[mi][ji]);
    __builtin_amdgcn_s_barrier();  // reads of buf[cur] done before overwrite
  }
#undef STAGE_A
#pragma unroll
  for (int mi = 0; mi < 4; ++mi)
#pragma unroll
    for (int ji = 0; ji < 4; ++ji) {
      int j = j0 + wj * 64 + ji * 16 + l15;
#pragma unroll
      for (int r = 0; r < 4; ++r) {
        int m = m0 + wm * 64 + mi * 16 + quad * 4 + r;
        G[m * 16384 + j] = f2b(acc[mi][ji][r]);
      }
    }
}

// ---------------- GCN phase B (layers 1-2): per-node MFMA weight apply ---
// Hrm output staged in LDS -> dense uint4 global stores; H8out scatter.
__global__ void __launch_bounds__(256) gcn_phaseB(
    const unsigned short* __restrict__ Hrm, const unsigned short* __restrict__ G,
    const unsigned short* __restrict__ W8, const float* __restrict__ biasn,
    unsigned short* __restrict__ H8out, unsigned short* __restrict__ Hrmout) {
  __shared__ unsigned short stage[8192];  // 16 KB output staging
  int bid = blockIdx.x;  // 1024 = n(512) x bh(2)
  int n = bid >> 1, bh = bid & 1;
  int tid = threadIdx.x;
  int lane = tid & 63, wave = tid >> 6, l15 = lane & 15, quad = lane >> 4;
  short8 wb[3][2];
#pragma unroll
  for (int s = 0; s < 3; ++s)
#pragma unroll
    for (int nt = 0; nt < 2; ++nt)
      wb[s][nt] = *(const short8*)&W8[(n * 3 + s) * 1024 + quad * 256 +
                                      (nt * 16 + l15) * 8];
  float b0 = biasn[n * 32 + l15], b1 = biasn[n * 32 + 16 + l15];
  int n8base = (n >> 3) * 131072 + (n & 7);
#pragma unroll
  for (int mi = 0; mi < 4; ++mi) {
    int btl0 = wave * 64 + mi * 16;        // local bt within this bh half
    int bt0 = bh * 256 + btl0;
    int btl = bt0 + l15;
    short8 a0 = *(const short8*)&Hrm[n * 16384 + btl * 32 + quad * 8];
    short8 a1 = *(const short8*)&G[n * 16384 + btl * 32 + quad * 8];
    short8 a2 = *(const short8*)&G[(512 + n) * 16384 + btl * 32 + quad * 8];
    float4v acc0 = MFMA32(a0, wb[0][0], (float4v)0.f);
    acc0 = MFMA32(a1, wb[1][0], acc0);
    acc0 = MFMA32(a2, wb[2][0], acc0);
    float4v acc1 = MFMA32(a0, wb[0][1], (float4v)0.f);
    acc1 = MFMA32(a1, wb[1][1], acc1);
    acc1 = MFMA32(a2, wb[2][1], acc1);
#pragma unroll
    for (int r = 0; r < 4; ++r) {
      int bt = bt0 + quad * 4 + r;
      int bl = btl0 + quad * 4 + r;        // in [0,256)
      unsigned short v0 = f2b(acc0[r] + b0);
      unsigned short v1 = f2b(acc1[r] + b1);
      H8out[n8base + (bt * 32 + l15) * 8] = v0;
      H8out[n8base + (bt * 32 + 16 + l15) * 8] = v1;
      stage[bl * 32 + l15] = v0;
      stage[bl * 32 + 16 + l15] = v1;
    }
  }
  __syncthreads();
  unsigned short* dst = Hrmout + n * 16384 + bh * 8192;
#pragma unroll
  for (int it = 0; it < 4; ++it) {
    int i16 = it * 256 + tid;
    *(uint4*)&dst[i16 * 8] = *(const uint4*)&stage[i16 * 8];
  }
}

// ---------------- GCN phase B layer-3 FUSED with TCN ---------------------
// Block (n,bh) computes GCN-layer-3 output for b in {2bh, 2bh+1} (full T),
// writes it directly into the TCN's zero-padded LDS layout, runs the 3
// temporal blocks (2 waves per b, nt split, barrier per conv stage), and
// stores the attn-input layout. Removes the tcn launch + 33 MB HBM trip.
__global__ void __launch_bounds__(256) gcn_phaseB_tcn(
    const unsigned short* __restrict__ Hrm, const unsigned short* __restrict__ G,
    const unsigned short* __restrict__ W8, const float* __restrict__ biasn,
    const unsigned short* __restrict__ Wt,
    const float* __restrict__ b1g, const float* __restrict__ b2g,
    unsigned short* __restrict__ yout) {
  __shared__ unsigned short Y8f[2][4352];
  __shared__ unsigned short O8f[2][4352];
  int bid = blockIdx.x;  // 1024 = n(512) x bh(2)
  int n = bid >> 1, bh = bid & 1;
  int tid = threadIdx.x;
  int lane = tid & 63, wave = tid >> 6, l15 = lane & 15, quad = lane >> 4;
  int b_local = wave >> 1, half = wave & 1;
  // zero the t-pad slots (t-slot 0..7) of both buffers (idempotent per pair)
  {
    int cg = lane >> 4, t = (lane >> 1) & 7, hf = lane & 1;
    ushort4 z = {0, 0, 0, 0};
    *(ushort4*)&Y8f[b_local][(cg * 136 + t) * 8 + hf * 4] = z;
    *(ushort4*)&O8f[b_local][(cg * 136 + t) * 8 + hf * 4] = z;
  }
  // ---- GCN layer-3 weight apply; epilogue writes y8 layout directly ----
  short8 wb[3][2];
#pragma unroll
  for (int s = 0; s < 3; ++s)
#pragma unroll
    for (int nt = 0; nt < 2; ++nt)
      wb[s][nt] = *(const short8*)&W8[(n * 3 + s) * 1024 + quad * 256 +
                                      (nt * 16 + l15) * 8];
  float b0 = biasn[n * 32 + l15], b1 = biasn[n * 32 + 16 + l15];
#pragma unroll
  for (int mi = 0; mi < 4; ++mi) {
    int btl0 = wave * 64 + mi * 16;
    int btl = bh * 256 + btl0 + l15;
    short8 a0 = *(const short8*)&Hrm[n * 16384 + btl * 32 + quad * 8];
    short8 a1 = *(const short8*)&G[n * 16384 + btl * 32 + quad * 8];
    short8 a2 = *(const short8*)&G[(512 + n) * 16384 + btl * 32 + quad * 8];
    float4v acc0 = MFMA32(a0, wb[0][0], (float4v)0.f);
    acc0 = MFMA32(a1, wb[1][0], acc0);
    acc0 = MFMA32(a2, wb[2][0], acc0);
    float4v acc1 = MFMA32(a0, wb[0][1], (float4v)0.f);
    acc1 = MFMA32(a1, wb[1][1], acc1);
    acc1 = MFMA32(a2, wb[2][1], acc1);
#pragma unroll
    for (int r = 0; r < 4; ++r) {
      int bl = btl0 + quad * 4 + r;       // in [0,256)
      int blb = bl >> 7, t = bl & 127;    // b_local of this row, time index
      unsigned short v0 = f2b(acc0[r] + b0);
      unsigned short v1 = f2b(acc1[r] + b1);
      // c = l15 -> cg = l15>>3; c = 16+l15 -> cg = 2+(l15>>3)
      Y8f[blb][(((l15 >> 3)) * 136 + t + 8) * 8 + (l15 & 7)] = v0;
      Y8f[blb][((2 + (l15 >> 3)) * 136 + t + 8) * 8 + (l15 & 7)] = v1;
    }
  }
  __syncthreads();
  // ---- TCN: 2 waves per b, nt range split by half ----
  unsigned short* y8 = &Y8f[b_local][0];
  unsigned short* o8 = &O8f[b_local][0];
  for (int blk = 0; blk < 3; ++blk) {
    int dil = 1 << blk;
    for (int conv = 0; conv < 2; ++conv) {
      const unsigned short* wbase = Wt + ((blk * 2 + conv) * 3) * 1024;
      short8 af[2][3];
#pragma unroll
      for (int mt = 0; mt < 2; ++mt)
#pragma unroll
        for (int kk = 0; kk < 3; ++kk)
          af[mt][kk] = *(const short8*)&wbase[kk * 1024 +
                                              (mt * 16 + l15) * 32 + quad * 8];
      const float* bias = (conv ? b2g : b1g) + blk * 32;
      float4 bs0 = *(const float4*)&bias[quad * 4];
      float4 bs1 = *(const float4*)&bias[16 + quad * 4];
      float bb0[4] = {bs0.x, bs0.y, bs0.z, bs0.w};
      float bb1[4] = {bs1.x, bs1.y, bs1.z, bs1.w};
      const unsigned short* rbuf = conv ? o8 : y8;
#pragma unroll
      for (int ntq = 0; ntq < 4; ++ntq) {
        int nt = half * 4 + ntq;
        float4v acc0 = (float4v)0.f, acc1 = (float4v)0.f;
#pragma unroll
        for (int kk = 0; kk < 3; ++kk) {
          int tb = nt * 16 + l15 + 8 - (2 - kk) * dil;
          short8 bf = *(const short8*)&rbuf[(quad * 136 + tb) * 8];
          acc0 = MFMA32(af[0][kk], bf, acc0);
          acc1 = MFMA32(af[1][kk], bf, acc1);
        }
        int t8 = nt * 16 + l15 + 8;
        int og0 = (quad >> 1), ci0 = (quad & 1) * 4;
        if (conv == 0) {
          ushort4 w0 = f2b4(fmaxf(acc0[0] + bb0[0], 0.f),
                            fmaxf(acc0[1] + bb0[1], 0.f),
                            fmaxf(acc0[2] + bb0[2], 0.f),
                            fmaxf(acc0[3] + bb0[3], 0.f));
          ushort4 w1 = f2b4(fmaxf(acc1[0] + bb1[0], 0.f),
                            fmaxf(acc1[1] + bb1[1], 0.f),
                            fmaxf(acc1[2] + bb1[2], 0.f),
                            fmaxf(acc1[3] + bb1[3], 0.f));
          *(ushort4*)&o8[((og0)*136 + t8) * 8 + ci0] = w0;
          *(ushort4*)&o8[((2 + og0) * 136 + t8) * 8 + ci0] = w1;
        } else {
          ushort4 y0 = *(const ushort4*)&y8[((og0)*136 + t8) * 8 + ci0];
          ushort4 y1 = *(const ushort4*)&y8[((2 + og0) * 136 + t8) * 8 + ci0];
          ushort4 w0 = f2b4(
              fmaxf(fmaxf(acc0[0] + bb0[0], 0.f) + b2f(y0.x), 0.f),
              fmaxf(fmaxf(acc0[1] + bb0[1], 0.f) + b2f(y0.y), 0.f),
              fmaxf(fmaxf(acc0[2] + bb0[2], 0.f) + b2f(y0.z), 0.f),
              fmaxf(fmaxf(acc0[3] + bb0[3], 0.f) + b2f(y0.w), 0.f));
          ushort4 w1 = f2b4(
              fmaxf(fmaxf(acc1[0] + bb1[0], 0.f) + b2f(y1.x), 0.f),
              fmaxf(fmaxf(acc1[1] + bb1[1], 0.f) + b2f(y1.y), 0.f),
              fmaxf(fmaxf(acc1[2] + bb1[2], 0.f) + b2f(y1.z), 0.f),
              fmaxf(fmaxf(acc1[3] + bb1[3], 0.f) + b2f(y1.w), 0.f));
          *(ushort4*)&y8[((og0)*136 + t8) * 8 + ci0] = w0;
          *(ushort4*)&y8[((2 + og0) * 136 + t8) * 8 + ci0] = w1;
        }
      }
      __syncthreads();  // cross-half reads of the buffer written this stage
    }
  }
  // ---- store attn-input layout ----
  unsigned short* dst = yout + n * 16384 + (bh * 2 + b_local) * 4096;
#pragma unroll
  for (int pp = 0; pp < 4; ++pp) {
    int e = (half * 4 + pp) * 64 + lane;
    int og = e >> 7, t = e & 127;
    *(uint4*)&dst[t * 32 + og * 8] = *(const uint4*)&y8[(og * 136 + t + 8) * 8];
  }
}

// ---------------- attention: 512 threads, 1 q-tile per wave --------------
// (R5-exact build: serial LN, tree-max softmax -- measured 64 VGPR,
//  8 waves/SIMD; E[x^2] variant pushed VGPR to 68 and lost a wave.)
__global__ void __launch_bounds__(512) attn_kernel(
    const unsigned short* __restrict__ yin,  // bf16 [n][b][t*32+d]
    float* __restrict__ outp,
    const unsigned short* __restrict__ Wf,   // precomputed bf16 frags
    const float* __restrict__ gg, const float* __restrict__ bgb) {
  __shared__ unsigned short hfrag[4096];     // h in A32-frag layout (+residual)
  __shared__ unsigned short KbOb[5120];      // Kb[128][36] / Ob[128][40] aliased
  __shared__ unsigned short QT[32 * 136];    // Q^T [d][t], pad 136
  __shared__ unsigned short VT[32 * 136];    // V^T [d][kt], pad 136
  int bn = blockIdx.x, tid = threadIdx.x;
  int b = bn >> 9, n = bn & 511;
  int lane = tid & 63, wave = tid >> 6;     // wave = q-tile (0..7)
  int l15 = lane & 15, quad = lane >> 4;
  int mtq = wave;

  // glds staging: dest = q*16B (linear per lane); q->(t,cb) remap bijective
  {
    int q = tid;
    int t = ((q >> 6) << 4) | (q & 15);
    int cb = (q >> 4) & 3;
    glds16(&yin[n * 16384 + b * 4096 + (t * 4 + cb) * 8], &hfrag[q * 8]);
  }

  for (int L = 0; L < 2; ++L) {
    short8 wf[4][2];
#pragma unroll
    for (int mat = 0; mat < 4; ++mat)
#pragma unroll
      for (int nt = 0; nt < 2; ++nt)
        wf[mat][nt] =
            *(const short8*)&Wf[(((L * 4 + mat) * 2 + nt) * 64 + lane) * 8];
    __syncthreads();  // L0: hfrag staged (vmcnt drain); L1: prev reads done
    // ---- projections; write K row-major, Q^T/V^T transposed (b64) ----
    {
      short8 af = *(const short8*)&hfrag[(mtq * 4 + quad) * 128 + l15 * 8];
      int tbase = mtq * 16 + quad * 4;
#pragma unroll
      for (int nt = 0; nt < 2; ++nt) {
        float4v qa = MFMA32(af, wf[0][nt], (float4v)0.f);
        float4v ka = MFMA32(af, wf[1][nt], (float4v)0.f);
        float4v va = MFMA32(af, wf[2][nt], (float4v)0.f);
        int d = nt * 16 + l15;
#pragma unroll
        for (int r = 0; r < 4; ++r) KbOb[(tbase + r) * 36 + d] = f2b(ka[r]);
        *(ushort4*)&QT[d * 136 + tbase] = f2b4(qa[0], qa[1], qa[2], qa[3]);
        *(ushort4*)&VT[d * 136 + tbase] = f2b4(va[0], va[1], va[2], va[3]);
      }
    }
    __syncthreads();  // frags ready
    // ---- scores (S^T = K @ Q^T), softmax, PV ----
    float4v oaccT[2];
#pragma unroll
    for (int hh = 0; hh < 2; ++hh) oaccT[hh] = (float4v)0.f;
    for (int hh = 0; hh < 2; ++hh) {
      short4v qb;
#pragma unroll
      for (int jj = 0; jj < 4; ++jj)
        qb[jj] = (short)QT[(hh * 16 + quad * 4 + jj) * 136 + mtq * 16 + l15];
      float4v sacc[8];
#pragma unroll
      for (int st = 0; st < 8; ++st) {
        short4v ka = *(const short4v*)&KbOb[(st * 16 + l15) * 36 + hh * 16 +
                                            quad * 4];
        sacc[st] = MFMA16A(ka, qb, (float4v)0.f);
      }
      float tmx[8];
#pragma unroll
      for (int st = 0; st < 8; ++st)
        tmx[st] = fmaxf(fmaxf(sacc[st][0], sacc[st][1]),
                        fmaxf(sacc[st][2], sacc[st][3]));
      float mx = fmaxf(fmaxf(fmaxf(tmx[0], tmx[1]), fmaxf(tmx[2], tmx[3])),
                       fmaxf(fmaxf(tmx[4], tmx[5]), fmaxf(tmx[6], tmx[7])));
      mx = fmaxf(mx, __shfl_xor(mx, 16));
      mx = fmaxf(mx, __shfl_xor(mx, 32));
      float ps[8];
#pragma unroll
      for (int st = 0; st < 8; ++st) {
#pragma unroll
        for (int r = 0; r < 4; ++r) sacc[st][r] = EXP2F(sacc[st][r] - mx);
        ps[st] = (sacc[st][0] + sacc[st][1]) + (sacc[st][2] + sacc[st][3]);
      }
      float sum = ((ps[0] + ps[1]) + (ps[2] + ps[3])) +
                  ((ps[4] + ps[5]) + (ps[6] + ps[7]));
      sum += __shfl_xor(sum, 16);
      sum += __shfl_xor(sum, 32);
      float inv = 1.f / sum;
      // P stored unnormalized; 1/sum folded into O accumulator after PV
#pragma unroll
      for (int st = 0; st < 8; ++st) {
        union { unsigned int u[2]; short4v s; } pv;
        pv.u[0] = f2b2(sacc[st][0], sacc[st][1]);
        pv.u[1] = f2b2(sacc[st][2], sacc[st][3]);
        short4v va = *(const short4v*)&VT[(hh * 16 + l15) * 136 + st * 16 +
                                          quad * 4];
        oaccT[hh] = MFMA16A(va, pv.s, oaccT[hh]);
      }
#pragma unroll
      for (int r = 0; r < 4; ++r) oaccT[hh][r] *= inv;
    }
    __syncthreads();  // all Kb reads done before Ob overwrites the buffer
    // ---- O^T C-frag -> O row-major (b64, wave-local rows) ----
#pragma unroll
    for (int hh = 0; hh < 2; ++hh)
      *(ushort4*)&KbOb[(mtq * 16 + l15) * 40 + hh * 16 + quad * 4] =
          f2b4(oaccT[hh][0], oaccT[hh][1], oaccT[hh][2], oaccT[hh][3]);
    // ---- output projection + residual + layernorm ----
    float gam0 = gg[L * 32 + l15], bet0 = bgb[L * 32 + l15];
    float gam1 = gg[L * 32 + 16 + l15], bet1 = bgb[L * 32 + 16 + l15];
    {
      short8 ofa = *(const short8*)&KbOb[(mtq * 16 + l15) * 40 + quad * 8];
      float4v racc0 = MFMA32(ofa, wf[3][0], (float4v)0.f);
      float4v racc1 = MFMA32(ofa, wf[3][1], (float4v)0.f);
      int hi0 = (mtq * 4 + (l15 >> 3)) * 128 + (l15 & 7);
      int hi1 = (mtq * 4 + 2 + (l15 >> 3)) * 128 + (l15 & 7);
#pragma unroll
      for (int r = 0; r < 4; ++r) {
        int t = mtq * 16 + quad * 4 + r;
        int ro = (quad * 4 + r) * 8;
        float v0 = racc0[r] + b2f(hfrag[hi0 + ro]);
        float v1 = racc1[r] + b2f(hfrag[hi1 + ro]);
        float s = v0 + v1;
        for (int m = 1; m < 16; m <<= 1) s += __shfl_xor(s, m);
        float mu = s * 0.03125f;
        float d0 = v0 - mu, d1 = v1 - mu;
        float q = d0 * d0 + d1 * d1;
        for (int m = 1; m < 16; m <<= 1) q += __shfl_xor(q, m);
        float rs = rsqrtf(q * 0.03125f + 1e-5f);
        float y0 = d0 * rs * gam0 + bet0;
        float y1 = d1 * rs * gam1 + bet1;
        if (L == 0) {
          hfrag[hi0 + ro] = f2b(y0);  // wave-local rows; no barrier needed
          hfrag[hi1 + ro] = f2b(y1);
        } else {
          outp[((b * 128 + t) * 512 + n) * 32 + l15] = y0;
          outp[((b * 128 + t) * 512 + n) * 32 + 16 + l15] = y1;
        }
      }
    }
  }
}

extern "C" void kernel_launch(void* const* d_in, const int* in_sizes, int n_in,
                              void* d_out, int out_size, void* d_ws, size_t ws_size,
                              hipStream_t stream) {
  const float* x    = (const float*)d_in[0];
  const float* emb  = (const float*)d_in[2];
  const float* adj  = (const float*)d_in[3];
  const float* gw   = (const float*)d_in[4];
  const float* gb   = (const float*)d_in[5];
  const float* tw1  = (const float*)d_in[6];
  const float* tb1  = (const float*)d_in[7];
  const float* tw2  = (const float*)d_in[8];
  const float* tb2  = (const float*)d_in[9];
  const float* wq   = (const float*)d_in[10];
  const float* wk   = (const float*)d_in[11];
  const float* wv   = (const float*)d_in[12];
  const float* wo   = (const float*)d_in[13];
  const float* tg   = (const float*)d_in[14];
  const float* tbb  = (const float*)d_in[15];
  float* outp = (float*)d_out;

  char* p = (char*)d_ws;
  unsigned short* Sb  = (unsigned short*)p; p += 1048576;
  unsigned short* W8  = (unsigned short*)p; p += 9437184;
  float* biasn        = (float*)p;          p += 196608;
  unsigned short* G   = (unsigned short*)p; p += 33554432;
  unsigned short* H8a = (unsigned short*)p; p += 16777216;
  unsigned short* H8b = (unsigned short*)p; p += 16777216;
  unsigned short* Hra = (unsigned short*)p; p += 16777216;
  unsigned short* Hrb = (unsigned short*)p; p += 16777216;
  unsigned short* Wt  = (unsigned short*)p; p += 36864;
  unsigned short* Wf  = (unsigned short*)p; p += 16384;  // ~111.4 MB total

  prep_all<<<dim3(2166), dim3(256), 0, stream>>>(
      adj, Sb, emb, gw, gb, W8, biasn, tw1, tw2, Wt, wq, wk, wv, wo, Wf,
      x, H8a, Hra);

  gcn_phaseA<<<dim3(512), dim3(512), 0, stream>>>(Sb, H8a, G);
  gcn_phaseB<<<dim3(1024), dim3(256), 0, stream>>>(
      Hra, G, W8, biasn, H8b, Hrb);
  gcn_phaseA<<<dim3(512), dim3(512), 0, stream>>>(Sb, H8b, G);
  gcn_phaseB<<<dim3(1024), dim3(256), 0, stream>>>(
      Hrb, G, W8 + 1572864, biasn + 16384, H8a, Hra);
  gcn_phaseA<<<dim3(512), dim3(512), 0, stream>>>(Sb, H8a, G);
  // layer-3 weight apply fused with the full TCN stack; writes attn input
  gcn_phaseB_tcn<<<dim3(1024), dim3(256), 0, stream>>>(
      Hra, G, W8 + 3145728, biasn + 32768, Wt, tb1, tb2, H8b);

  attn_kernel<<<dim3(2048), dim3(512), 0, stream>>>(H8b, outp, Wf, tg, tbb);
}

// Round 11
// 336.944 us; speedup vs baseline: 1.0702x; 1.0069x over previous
//
#include <hip/hip_runtime.h>
#include <hip/hip_bf16.h>

// B=4, T=128, N=512, D=32, CHEB_K=3, EMB=10, HEADS=2, TA_LAYERS=2, GCN_NUM=3,
// TCN_BLOCKS=3, KSIZE=3.  Inputs/outputs fp32; internal bf16 + MFMA.
// R11 = R9 known-good (339.3us) + T5 setprio around attn MFMA clusters.
// (R10's cooperative mega-kernel hung the container: hipLaunchCooperativeKernel
//  is incompatible with the harness's graph capture -- path closed.)

typedef __attribute__((ext_vector_type(8))) short short8;
typedef __attribute__((ext_vector_type(4))) short short4v;
typedef __attribute__((ext_vector_type(4))) float float4v;

#define MFMA32(a, b, c) __builtin_amdgcn_mfma_f32_16x16x32_bf16((a), (b), (c), 0, 0, 0)
#if defined(__has_builtin)
#if __has_builtin(__builtin_amdgcn_mfma_f32_16x16x16_bf16)
#define MFMA16A(a, b, c) __builtin_amdgcn_mfma_f32_16x16x16_bf16((a), (b), (c), 0, 0, 0)
#endif
#endif
#ifndef MFMA16A
#define MFMA16A(a, b, c) __builtin_amdgcn_mfma_f32_16x16x16bf16_1k((a), (b), (c), 0, 0, 0)
#endif

#if defined(__has_builtin)
#if __has_builtin(__builtin_amdgcn_exp2f)
#define EXP2F(x) __builtin_amdgcn_exp2f(x)
#endif
#endif
#ifndef EXP2F
#define EXP2F(x) exp2f(x)
#endif

typedef const __attribute__((address_space(1))) unsigned int* gas_ptr;
typedef __attribute__((address_space(3))) unsigned int* las_ptr;
__device__ __forceinline__ void glds16(const void* g, void* l) {
  __builtin_amdgcn_global_load_lds((gas_ptr)g, (las_ptr)l, 16, 0, 0);
}

// packed fp32x2 -> bf16x2 (v_cvt_pk_bf16_f32 on gfx950), RNE
__device__ __forceinline__ unsigned int f2b2(float lo, float hi) {
  union { __hip_bfloat162 h; unsigned int u; } cv;
  cv.h = __float22bfloat162_rn(make_float2(lo, hi));
  return cv.u;
}
// single fp32 -> bf16 via cvt_pk (1 VALU op vs 4 for manual RNE)
__device__ __forceinline__ unsigned short f2b(float f) {
  return (unsigned short)f2b2(f, f);
}
__device__ __forceinline__ float b2f(unsigned short u) {
  return __uint_as_float(((unsigned int)u) << 16);
}
__device__ __forceinline__ ushort4 f2b4(float a, float b, float c, float d) {
  union { unsigned int u[2]; ushort4 s; } cv;
  cv.u[0] = f2b2(a, b);
  cv.u[1] = f2b2(c, d);
  return cv.s;
}

// ================= fused prep: all independent preprocessing ==============
__global__ void __launch_bounds__(256) prep_all(
    const float* __restrict__ adj, unsigned short* __restrict__ Sb,
    const float* __restrict__ emb, const float* __restrict__ gw,
    const float* __restrict__ gb, unsigned short* __restrict__ W8,
    float* __restrict__ biasn,
    const float* __restrict__ w1g, const float* __restrict__ w2g,
    unsigned short* __restrict__ Wt,
    const float* __restrict__ wqg, const float* __restrict__ wkg,
    const float* __restrict__ wvg, const float* __restrict__ wog,
    unsigned short* __restrict__ Wf,
    const float* __restrict__ x, unsigned short* __restrict__ H8,
    unsigned short* __restrict__ Hrm) {
  __shared__ unsigned short Asq[128 * 40];
  __shared__ unsigned short Bsq[128 * 40];
  int bid = blockIdx.x, tid = threadIdx.x;

  if (bid < 64) {
    int base = bid * 4096;
#pragma unroll
    for (int it = 0; it < 4; ++it) {
      int e = base + it * 1024 + tid * 4;
      float4 v = *(const float4*)&adj[e];
      union { unsigned int u[2]; ushort4 s; } pk;
      pk.u[0] = f2b2(v.x, v.y);
      pk.u[1] = f2b2(v.z, v.w);
      *(ushort4*)&Sb[e] = pk.s;
    }
    return;
  }
  if (bid < 80) {
    // ---- A^2 via MFMA: 128x128 tile, K=512 in 16 steps ----
    int tb = bid - 64;
    int mt = tb >> 2, jt = tb & 3;
    int m0 = mt * 128, j0 = jt * 128;
    int wave = tid >> 6, lane = tid & 63;
    int wm = wave >> 1, wj = wave & 1;
    int l15 = lane & 15, quad = lane >> 4;
    float4v acc[4][4];
#pragma unroll
    for (int a = 0; a < 4; ++a)
#pragma unroll
      for (int b = 0; b < 4; ++b) acc[a][b] = (float4v)0.f;
    for (int kt = 0; kt < 512; kt += 32) {
#pragma unroll
      for (int p = 0; p < 16; ++p) {
        int idx = p * 256 + tid;
        int m = idx >> 5, k = idx & 31;
        Asq[m * 40 + k] = f2b(adj[(m0 + m) * 512 + kt + k]);
      }
#pragma unroll
      for (int p = 0; p < 16; ++p) {
        int idx = p * 256 + tid;
        int k = idx >> 7, j = idx & 127;
        Bsq[j * 40 + k] = f2b(adj[(kt + k) * 512 + j0 + j]);
      }
      __syncthreads();
      short8 af[4], bfr[4];
#pragma unroll
      for (int mi = 0; mi < 4; ++mi)
        af[mi] = *(const short8*)&Asq[(wm * 64 + mi * 16 + l15) * 40 + quad * 8];
#pragma unroll
      for (int ji = 0; ji < 4; ++ji)
        bfr[ji] = *(const short8*)&Bsq[(wj * 64 + ji * 16 + l15) * 40 + quad * 8];
#pragma unroll
      for (int mi = 0; mi < 4; ++mi)
#pragma unroll
        for (int ji = 0; ji < 4; ++ji)
          acc[mi][ji] = MFMA32(af[mi], bfr[ji], acc[mi][ji]);
      __syncthreads();
    }
#pragma unroll
    for (int mi = 0; mi < 4; ++mi)
#pragma unroll
      for (int ji = 0; ji < 4; ++ji) {
        int j = j0 + wj * 64 + ji * 16 + l15;
#pragma unroll
        for (int r = 0; r < 4; ++r) {
          int m = m0 + wm * 64 + mi * 16 + quad * 4 + r;
          Sb[(512 + m) * 512 + j] =
              f2b(2.f * acc[mi][ji][r] - (m == j ? 1.f : 0.f));
        }
      }
    return;
  }
  if (bid < 1616) {
    int b2 = bid - 80;
    int i = b2 >> 9, n = b2 & 511;
    float ev[10];
#pragma unroll
    for (int e = 0; e < 10; ++e) ev[e] = emb[n * 10 + e];
    for (int idx = tid; idx < 3072; idx += 256) {
      int s = idx >> 10, c = (idx >> 5) & 31, o = idx & 31;
      float acc = 0.f;
#pragma unroll
      for (int e = 0; e < 10; ++e) acc += ev[e] * gw[(i * 10 + e) * 3072 + idx];
      W8[((i * 512 + n) * 3 + s) * 1024 + (c >> 3) * 256 + o * 8 + (c & 7)] =
          f2b(acc);
    }
    if (tid < 32) {
      float acc = 0.f;
#pragma unroll
      for (int e = 0; e < 10; ++e) acc += ev[e] * gb[(i * 10 + e) * 32 + tid];
      biasn[(i * 512 + n) * 32 + tid] = acc;
    }
    return;
  }
  if (bid < 1622) {
    int b2 = bid - 1616;
    int blk = b2 >> 1, conv = b2 & 1;
    const float* w = (conv ? w2g : w1g) + blk * 3072;
    for (int idx = tid; idx < 3072; idx += 256) {
      int kk = idx >> 10, rem = idx & 1023;
      int o = rem >> 5, c = rem & 31;
      Wt[b2 * 3072 + idx] = f2b(w[o * 96 + c * 3 + kk]);
    }
    return;
  }
  if (bid < 1654) {
    int idx = (bid - 1622) * 256 + tid;
    int L = idx >> 12;
    int mat = (idx >> 10) & 3;
    int nt = (idx >> 9) & 1;
    int lane = (idx >> 3) & 63;
    int j = idx & 7;
    int quad = lane >> 4, l15 = lane & 15;
    const float* base =
        (mat == 0 ? wqg : mat == 1 ? wkg : mat == 2 ? wvg : wog) + L * 1024;
    float v = base[(quad * 8 + j) * 32 + nt * 16 + l15];
    if (mat == 0) v *= 0.36067376022224085f;
    Wf[idx] = f2b(v);
    return;
  }
  {
    int b2 = bid - 1654;  // 512 = nblk(64) x part(8)
    int nblk = b2 >> 3, part = b2 & 7;
    for (int qq = tid; qq < 2048; qq += 256) {
      int q = part * 2048 + qq;
      int bt = q >> 5, c = q & 31;
      const float* xb = x + bt * 16384 + nblk * 256 + c;
      float f[8];
#pragma unroll
      for (int s = 0; s < 8; ++s) f[s] = xb[s * 32];
      union { unsigned int u[4]; uint4 v; } pk;
      pk.u[0] = f2b2(f[0], f[1]);
      pk.u[1] = f2b2(f[2], f[3]);
      pk.u[2] = f2b2(f[4], f[5]);
      pk.u[3] = f2b2(f[6], f[7]);
      *(uint4*)&H8[nblk * 131072 + q * 8] = pk.v;
    }
    for (int qq = tid; qq < 2048; qq += 256) {
      int q = part * 2048 + qq;
      int s = q >> 11, e0 = (q & 2047) * 8;
      int bt = e0 >> 5, c0 = e0 & 31;
      const float* xb = x + bt * 16384 + (nblk * 8 + s) * 32 + c0;
      float4 v0 = *(const float4*)&xb[0];
      float4 v1 = *(const float4*)&xb[4];
      union { unsigned int u[4]; uint4 v; } pk;
      pk.u[0] = f2b2(v0.x, v0.y);
      pk.u[1] = f2b2(v0.z, v0.w);
      pk.u[2] = f2b2(v1.x, v1.y);
      pk.u[3] = f2b2(v1.z, v1.w);
      *(uint4*)&Hrm[(nblk * 8 + s) * 16384 + e0] = pk.v;
    }
  }
}

// ---------------- GCN phase A: G = S @ H  (MFMA, bf16 out) --------------
// 256x128 tile, 512 threads / 8 waves, T4 counted-vmcnt pipeline.
__global__ void __launch_bounds__(512) gcn_phaseA(
    const unsigned short* __restrict__ Sb,
    const unsigned short* __restrict__ H8,
    unsigned short* __restrict__ G) {
  __shared__ unsigned short As[2][256 * 32];
  __shared__ unsigned short Bs[2][4096];
  int bid0 = blockIdx.x;  // 512
  int nb = (bid0 & 7) * 64 + (bid0 >> 3);  // XCD-contiguous, bijective
  int mt = nb & 3, jt = nb >> 2;
  int m0 = mt * 256, j0 = jt * 128;
  int tid = threadIdx.x;
  int wave = tid >> 6, lane = tid & 63;
  int wm = wave >> 1, wj = wave & 1;
  int l15 = lane & 15, quad = lane >> 4;
  float4v acc[4][4];
#pragma unroll
  for (int a = 0; a < 4; ++a)
#pragma unroll
    for (int b = 0; b < 4; ++b) acc[a][b] = (float4v)0.f;

  int qa0 = tid, qa1 = tid + 512;
  int ma0 = qa0 >> 2, ca0 = ((qa0 & 3) ^ ((qa0 >> 3) & 3)) * 8;
  int ma1 = qa1 >> 2, ca1 = ((qa1 & 3) ^ ((qa1 >> 3) & 3)) * 8;
  const unsigned short* sb0 = &Sb[(m0 + ma0) * 512 + ca0];
  const unsigned short* sb1 = &Sb[(m0 + ma1) * 512 + ca1];
  const unsigned short* hb0 = &H8[(tid >> 7) * 131072 + (j0 + (tid & 127)) * 8];

#define STAGE_A(buf, it2)                                   \
  {                                                         \
    int ncn = (it2) * 32;                                   \
    glds16(sb0 + ncn, &As[(buf)][qa0 * 8]);                 \
    glds16(sb1 + ncn, &As[(buf)][qa1 * 8]);                 \
    glds16(hb0 + (ncn >> 3) * 131072, &Bs[(buf)][tid * 8]); \
  }

  STAGE_A(0, 0);
  for (int it = 0; it < 16; ++it) {
    int cur = it & 1;
    if (it < 15) {
      STAGE_A(cur ^ 1, it + 1);
      asm volatile("s_waitcnt vmcnt(3)" ::: "memory");
    } else {
      asm volatile("s_waitcnt vmcnt(0)" ::: "memory");
    }
    __builtin_amdgcn_sched_barrier(0);
    __builtin_amdgcn_s_barrier();  // all waves' tile-cur loads landed
    short8 af[4], bfr[4];
#pragma unroll
    for (int mi = 0; mi < 4; ++mi) {
      int row = wm * 64 + mi * 16 + l15;
      int c8 = quad ^ ((row >> 1) & 3);  // read-side swizzle (same involution)
      af[mi] = *(const short8*)&As[cur][row * 32 + c8 * 8];
    }
#pragma unroll
    for (int ji = 0; ji < 4; ++ji)
      bfr[ji] =
          *(const short8*)&Bs[cur][quad * 1024 + (wj * 64 + ji * 16 + l15) * 8];
#pragma unroll
    for (int mi = 0; mi < 4; ++mi)
#pragma unroll
      for (int ji = 0; ji < 4; ++ji)
        acc[mi][ji] = MFMA32(af[mi], bfr[ji], acc[mi][ji]);
    __builtin_amdgcn_s_barrier();  // reads of buf[cur] done before overwrite
  }
#undef STAGE_A
#pragma unroll
  for (int mi = 0; mi < 4; ++mi)
#pragma unroll
    for (int ji = 0; ji < 4; ++ji) {
      int j = j0 + wj * 64 + ji * 16 + l15;
#pragma unroll
      for (int r = 0; r < 4; ++r) {
        int m = m0 + wm * 64 + mi * 16 + quad * 4 + r;
        G[m * 16384 + j] = f2b(acc[mi][ji][r]);
      }
    }
}

// ---------------- GCN phase B (layers 1-2): per-node MFMA weight apply ---
// Hrm output staged in LDS -> dense uint4 global stores; H8out scatter.
__global__ void __launch_bounds__(256) gcn_phaseB(
    const unsigned short* __restrict__ Hrm, const unsigned short* __restrict__ G,
    const unsigned short* __restrict__ W8, const float* __restrict__ biasn,
    unsigned short* __restrict__ H8out, unsigned short* __restrict__ Hrmout) {
  __shared__ unsigned short stage[8192];  // 16 KB output staging
  int bid = blockIdx.x;  // 1024 = n(512) x bh(2)
  int n = bid >> 1, bh = bid & 1;
  int tid = threadIdx.x;
  int lane = tid & 63, wave = tid >> 6, l15 = lane & 15, quad = lane >> 4;
  short8 wb[3][2];
#pragma unroll
  for (int s = 0; s < 3; ++s)
#pragma unroll
    for (int nt = 0; nt < 2; ++nt)
      wb[s][nt] = *(const short8*)&W8[(n * 3 + s) * 1024 + quad * 256 +
                                      (nt * 16 + l15) * 8];
  float b0 = biasn[n * 32 + l15], b1 = biasn[n * 32 + 16 + l15];
  int n8base = (n >> 3) * 131072 + (n & 7);
#pragma unroll
  for (int mi = 0; mi < 4; ++mi) {
    int btl0 = wave * 64 + mi * 16;        // local bt within this bh half
    int bt0 = bh * 256 + btl0;
    int btl = bt0 + l15;
    short8 a0 = *(const short8*)&Hrm[n * 16384 + btl * 32 + quad * 8];
    short8 a1 = *(const short8*)&G[n * 16384 + btl * 32 + quad * 8];
    short8 a2 = *(const short8*)&G[(512 + n) * 16384 + btl * 32 + quad * 8];
    float4v acc0 = MFMA32(a0, wb[0][0], (float4v)0.f);
    acc0 = MFMA32(a1, wb[1][0], acc0);
    acc0 = MFMA32(a2, wb[2][0], acc0);
    float4v acc1 = MFMA32(a0, wb[0][1], (float4v)0.f);
    acc1 = MFMA32(a1, wb[1][1], acc1);
    acc1 = MFMA32(a2, wb[2][1], acc1);
#pragma unroll
    for (int r = 0; r < 4; ++r) {
      int bt = bt0 + quad * 4 + r;
      int bl = btl0 + quad * 4 + r;        // in [0,256)
      unsigned short v0 = f2b(acc0[r] + b0);
      unsigned short v1 = f2b(acc1[r] + b1);
      H8out[n8base + (bt * 32 + l15) * 8] = v0;
      H8out[n8base + (bt * 32 + 16 + l15) * 8] = v1;
      stage[bl * 32 + l15] = v0;
      stage[bl * 32 + 16 + l15] = v1;
    }
  }
  __syncthreads();
  unsigned short* dst = Hrmout + n * 16384 + bh * 8192;
#pragma unroll
  for (int it = 0; it < 4; ++it) {
    int i16 = it * 256 + tid;
    *(uint4*)&dst[i16 * 8] = *(const uint4*)&stage[i16 * 8];
  }
}

// ---------------- GCN phase B layer-3 FUSED with TCN ---------------------
__global__ void __launch_bounds__(256) gcn_phaseB_tcn(
    const unsigned short* __restrict__ Hrm, const unsigned short* __restrict__ G,
    const unsigned short* __restrict__ W8, const float* __restrict__ biasn,
    const unsigned short* __restrict__ Wt,
    const float* __restrict__ b1g, const float* __restrict__ b2g,
    unsigned short* __restrict__ yout) {
  __shared__ unsigned short Y8f[2][4352];
  __shared__ unsigned short O8f[2][4352];
  int bid = blockIdx.x;  // 1024 = n(512) x bh(2)
  int n = bid >> 1, bh = bid & 1;
  int tid = threadIdx.x;
  int lane = tid & 63, wave = tid >> 6, l15 = lane & 15, quad = lane >> 4;
  int b_local = wave >> 1, half = wave & 1;
  {
    int cg = lane >> 4, t = (lane >> 1) & 7, hf = lane & 1;
    ushort4 z = {0, 0, 0, 0};
    *(ushort4*)&Y8f[b_local][(cg * 136 + t) * 8 + hf * 4] = z;
    *(ushort4*)&O8f[b_local][(cg * 136 + t) * 8 + hf * 4] = z;
  }
  short8 wb[3][2];
#pragma unroll
  for (int s = 0; s < 3; ++s)
#pragma unroll
    for (int nt = 0; nt < 2; ++nt)
      wb[s][nt] = *(const short8*)&W8[(n * 3 + s) * 1024 + quad * 256 +
                                      (nt * 16 + l15) * 8];
  float b0 = biasn[n * 32 + l15], b1 = biasn[n * 32 + 16 + l15];
#pragma unroll
  for (int mi = 0; mi < 4; ++mi) {
    int btl0 = wave * 64 + mi * 16;
    int btl = bh * 256 + btl0 + l15;
    short8 a0 = *(const short8*)&Hrm[n * 16384 + btl * 32 + quad * 8];
    short8 a1 = *(const short8*)&G[n * 16384 + btl * 32 + quad * 8];
    short8 a2 = *(const short8*)&G[(512 + n) * 16384 + btl * 32 + quad * 8];
    float4v acc0 = MFMA32(a0, wb[0][0], (float4v)0.f);
    acc0 = MFMA32(a1, wb[1][0], acc0);
    acc0 = MFMA32(a2, wb[2][0], acc0);
    float4v acc1 = MFMA32(a0, wb[0][1], (float4v)0.f);
    acc1 = MFMA32(a1, wb[1][1], acc1);
    acc1 = MFMA32(a2, wb[2][1], acc1);
#pragma unroll
    for (int r = 0; r < 4; ++r) {
      int bl = btl0 + quad * 4 + r;       // in [0,256)
      int blb = bl >> 7, t = bl & 127;    // b_local of this row, time index
      unsigned short v0 = f2b(acc0[r] + b0);
      unsigned short v1 = f2b(acc1[r] + b1);
      Y8f[blb][(((l15 >> 3)) * 136 + t + 8) * 8 + (l15 & 7)] = v0;
      Y8f[blb][((2 + (l15 >> 3)) * 136 + t + 8) * 8 + (l15 & 7)] = v1;
    }
  }
  __syncthreads();
  unsigned short* y8 = &Y8f[b_local][0];
  unsigned short* o8 = &O8f[b_local][0];
  for (int blk = 0; blk < 3; ++blk) {
    int dil = 1 << blk;
    for (int conv = 0; conv < 2; ++conv) {
      const unsigned short* wbase = Wt + ((blk * 2 + conv) * 3) * 1024;
      short8 af[2][3];
#pragma unroll
      for (int mt = 0; mt < 2; ++mt)
#pragma unroll
        for (int kk = 0; kk < 3; ++kk)
          af[mt][kk] = *(const short8*)&wbase[kk * 1024 +
                                              (mt * 16 + l15) * 32 + quad * 8];
      const float* bias = (conv ? b2g : b1g) + blk * 32;
      float4 bs0 = *(const float4*)&bias[quad * 4];
      float4 bs1 = *(const float4*)&bias[16 + quad * 4];
      float bb0[4] = {bs0.x, bs0.y, bs0.z, bs0.w};
      float bb1[4] = {bs1.x, bs1.y, bs1.z, bs1.w};
      const unsigned short* rbuf = conv ? o8 : y8;
#pragma unroll
      for (int ntq = 0; ntq < 4; ++ntq) {
        int nt = half * 4 + ntq;
        float4v acc0 = (float4v)0.f, acc1 = (float4v)0.f;
#pragma unroll
        for (int kk = 0; kk < 3; ++kk) {
          int tb = nt * 16 + l15 + 8 - (2 - kk) * dil;
          short8 bf = *(const short8*)&rbuf[(quad * 136 + tb) * 8];
          acc0 = MFMA32(af[0][kk], bf, acc0);
          acc1 = MFMA32(af[1][kk], bf, acc1);
        }
        int t8 = nt * 16 + l15 + 8;
        int og0 = (quad >> 1), ci0 = (quad & 1) * 4;
        if (conv == 0) {
          ushort4 w0 = f2b4(fmaxf(acc0[0] + bb0[0], 0.f),
                            fmaxf(acc0[1] + bb0[1], 0.f),
                            fmaxf(acc0[2] + bb0[2], 0.f),
                            fmaxf(acc0[3] + bb0[3], 0.f));
          ushort4 w1 = f2b4(fmaxf(acc1[0] + bb1[0], 0.f),
                            fmaxf(acc1[1] + bb1[1], 0.f),
                            fmaxf(acc1[2] + bb1[2], 0.f),
                            fmaxf(acc1[3] + bb1[3], 0.f));
          *(ushort4*)&o8[((og0)*136 + t8) * 8 + ci0] = w0;
          *(ushort4*)&o8[((2 + og0) * 136 + t8) * 8 + ci0] = w1;
        } else {
          ushort4 y0 = *(const ushort4*)&y8[((og0)*136 + t8) * 8 + ci0];
          ushort4 y1 = *(const ushort4*)&y8[((2 + og0) * 136 + t8) * 8 + ci0];
          ushort4 w0 = f2b4(
              fmaxf(fmaxf(acc0[0] + bb0[0], 0.f) + b2f(y0.x), 0.f),
              fmaxf(fmaxf(acc0[1] + bb0[1], 0.f) + b2f(y0.y), 0.f),
              fmaxf(fmaxf(acc0[2] + bb0[2], 0.f) + b2f(y0.z), 0.f),
              fmaxf(fmaxf(acc0[3] + bb0[3], 0.f) + b2f(y0.w), 0.f));
          ushort4 w1 = f2b4(
              fmaxf(fmaxf(acc1[0] + bb1[0], 0.f) + b2f(y1.x), 0.f),
              fmaxf(fmaxf(acc1[1] + bb1[1], 0.f) + b2f(y1.y), 0.f),
              fmaxf(fmaxf(acc1[2] + bb1[2], 0.f) + b2f(y1.z), 0.f),
              fmaxf(fmaxf(acc1[3] + bb1[3], 0.f) + b2f(y1.w), 0.f));
          *(ushort4*)&y8[((og0)*136 + t8) * 8 + ci0] = w0;
          *(ushort4*)&y8[((2 + og0) * 136 + t8) * 8 + ci0] = w1;
        }
      }
      __syncthreads();  // cross-half reads of the buffer written this stage
    }
  }
  unsigned short* dst = yout + n * 16384 + (bh * 2 + b_local) * 4096;
#pragma unroll
  for (int pp = 0; pp < 4; ++pp) {
    int e = (half * 4 + pp) * 64 + lane;
    int og = e >> 7, t = e & 127;
    *(uint4*)&dst[t * 32 + og * 8] = *(const uint4*)&y8[(og * 136 + t + 8) * 8];
  }
}

// ---------------- attention: 512 threads, 1 q-tile per wave --------------
// R5-exact structure (64 VGPR, 8 waves/SIMD) + T5 setprio on MFMA clusters.
__global__ void __launch_bounds__(512) attn_kernel(
    const unsigned short* __restrict__ yin,  // bf16 [n][b][t*32+d]
    float* __restrict__ outp,
    const unsigned short* __restrict__ Wf,   // precomputed bf16 frags
    const float* __restrict__ gg, const float* __restrict__ bgb) {
  __shared__ unsigned short hfrag[4096];     // h in A32-frag layout (+residual)
  __shared__ unsigned short KbOb[5120];      // Kb[128][36] / Ob[128][40] aliased
  __shared__ unsigned short QT[32 * 136];    // Q^T [d][t], pad 136
  __shared__ unsigned short VT[32 * 136];    // V^T [d][kt], pad 136
  int bn = blockIdx.x, tid = threadIdx.x;
  int b = bn >> 9, n = bn & 511;
  int lane = tid & 63, wave = tid >> 6;     // wave = q-tile (0..7)
  int l15 = lane & 15, quad = lane >> 4;
  int mtq = wave;

  {
    int q = tid;
    int t = ((q >> 6) << 4) | (q & 15);
    int cb = (q >> 4) & 3;
    glds16(&yin[n * 16384 + b * 4096 + (t * 4 + cb) * 8], &hfrag[q * 8]);
  }

  for (int L = 0; L < 2; ++L) {
    short8 wf[4][2];
#pragma unroll
    for (int mat = 0; mat < 4; ++mat)
#pragma unroll
      for (int nt = 0; nt < 2; ++nt)
        wf[mat][nt] =
            *(const short8*)&Wf[(((L * 4 + mat) * 2 + nt) * 64 + lane) * 8];
    __syncthreads();  // L0: hfrag staged (vmcnt drain); L1: prev reads done
    {
      short8 af = *(const short8*)&hfrag[(mtq * 4 + quad) * 128 + l15 * 8];
      int tbase = mtq * 16 + quad * 4;
#pragma unroll
      for (int nt = 0; nt < 2; ++nt) {
        float4v qa = MFMA32(af, wf[0][nt], (float4v)0.f);
        float4v ka = MFMA32(af, wf[1][nt], (float4v)0.f);
        float4v va = MFMA32(af, wf[2][nt], (float4v)0.f);
        int d = nt * 16 + l15;
#pragma unroll
        for (int r = 0; r < 4; ++r) KbOb[(tbase + r) * 36 + d] = f2b(ka[r]);
        *(ushort4*)&QT[d * 136 + tbase] = f2b4(qa[0], qa[1], qa[2], qa[3]);
        *(ushort4*)&VT[d * 136 + tbase] = f2b4(va[0], va[1], va[2], va[3]);
      }
    }
    __syncthreads();  // frags ready
    float4v oaccT[2];
#pragma unroll
    for (int hh = 0; hh < 2; ++hh) oaccT[hh] = (float4v)0.f;
    for (int hh = 0; hh < 2; ++hh) {
      short4v qb;
#pragma unroll
      for (int jj = 0; jj < 4; ++jj)
        qb[jj] = (short)QT[(hh * 16 + quad * 4 + jj) * 136 + mtq * 16 + l15];
      float4v sacc[8];
      __builtin_amdgcn_s_setprio(1);  // T5: favor the QK^T MFMA cluster
#pragma unroll
      for (int st = 0; st < 8; ++st) {
        short4v ka = *(const short4v*)&KbOb[(st * 16 + l15) * 36 + hh * 16 +
                                            quad * 4];
        sacc[st] = MFMA16A(ka, qb, (float4v)0.f);
      }
      __builtin_amdgcn_s_setprio(0);
      float tmx[8];
#pragma unroll
      for (int st = 0; st < 8; ++st)
        tmx[st] = fmaxf(fmaxf(sacc[st][0], sacc[st][1]),
                        fmaxf(sacc[st][2], sacc[st][3]));
      float mx = fmaxf(fmaxf(fmaxf(tmx[0], tmx[1]), fmaxf(tmx[2], tmx[3])),
                       fmaxf(fmaxf(tmx[4], tmx[5]), fmaxf(tmx[6], tmx[7])));
      mx = fmaxf(mx, __shfl_xor(mx, 16));
      mx = fmaxf(mx, __shfl_xor(mx, 32));
      float ps[8];
#pragma unroll
      for (int st = 0; st < 8; ++st) {
#pragma unroll
        for (int r = 0; r < 4; ++r) sacc[st][r] = EXP2F(sacc[st][r] - mx);
        ps[st] = (sacc[st][0] + sacc[st][1]) + (sacc[st][2] + sacc[st][3]);
      }
      float sum = ((ps[0] + ps[1]) + (ps[2] + ps[3])) +
                  ((ps[4] + ps[5]) + (ps[6] + ps[7]));
      sum += __shfl_xor(sum, 16);
      sum += __shfl_xor(sum, 32);
      float inv = 1.f / sum;
      // P stored unnormalized; 1/sum folded into O accumulator after PV
      __builtin_amdgcn_s_setprio(1);  // T5: favor the PV MFMA cluster
#pragma unroll
      for (int st = 0; st < 8; ++st) {
        union { unsigned int u[2]; short4v s; } pv;
        pv.u[0] = f2b2(sacc[st][0], sacc[st][1]);
        pv.u[1] = f2b2(sacc[st][2], sacc[st][3]);
        short4v va = *(const short4v*)&VT[(hh * 16 + l15) * 136 + st * 16 +
                                          quad * 4];
        oaccT[hh] = MFMA16A(va, pv.s, oaccT[hh]);
      }
      __builtin_amdgcn_s_setprio(0);
#pragma unroll
      for (int r = 0; r < 4; ++r) oaccT[hh][r] *= inv;
    }
    __syncthreads();  // all Kb reads done before Ob overwrites the buffer
#pragma unroll
    for (int hh = 0; hh < 2; ++hh)
      *(ushort4*)&KbOb[(mtq * 16 + l15) * 40 + hh * 16 + quad * 4] =
          f2b4(oaccT[hh][0], oaccT[hh][1], oaccT[hh][2], oaccT[hh][3]);
    float gam0 = gg[L * 32 + l15], bet0 = bgb[L * 32 + l15];
    float gam1 = gg[L * 32 + 16 + l15], bet1 = bgb[L * 32 + 16 + l15];
    {
      short8 ofa = *(const short8*)&KbOb[(mtq * 16 + l15) * 40 + quad * 8];
      float4v racc0 = MFMA32(ofa, wf[3][0], (float4v)0.f);
      float4v racc1 = MFMA32(ofa, wf[3][1], (float4v)0.f);
      int hi0 = (mtq * 4 + (l15 >> 3)) * 128 + (l15 & 7);
      int hi1 = (mtq * 4 + 2 + (l15 >> 3)) * 128 + (l15 & 7);
#pragma unroll
      for (int r = 0; r < 4; ++r) {
        int t = mtq * 16 + quad * 4 + r;
        int ro = (quad * 4 + r) * 8;
        float v0 = racc0[r] + b2f(hfrag[hi0 + ro]);
        float v1 = racc1[r] + b2f(hfrag[hi1 + ro]);
        float s = v0 + v1;
        for (int m = 1; m < 16; m <<= 1) s += __shfl_xor(s, m);
        float mu = s * 0.03125f;
        float d0 = v0 - mu, d1 = v1 - mu;
        float q = d0 * d0 + d1 * d1;
        for (int m = 1; m < 16; m <<= 1) q += __shfl_xor(q, m);
        float rs = rsqrtf(q * 0.03125f + 1e-5f);
        float y0 = d0 * rs * gam0 + bet0;
        float y1 = d1 * rs * gam1 + bet1;
        if (L == 0) {
          hfrag[hi0 + ro] = f2b(y0);  // wave-local rows; no barrier needed
          hfrag[hi1 + ro] = f2b(y1);
        } else {
          outp[((b * 128 + t) * 512 + n) * 32 + l15] = y0;
          outp[((b * 128 + t) * 512 + n) * 32 + 16 + l15] = y1;
        }
      }
    }
  }
}

extern "C" void kernel_launch(void* const* d_in, const int* in_sizes, int n_in,
                              void* d_out, int out_size, void* d_ws, size_t ws_size,
                              hipStream_t stream) {
  const float* x    = (const float*)d_in[0];
  const float* emb  = (const float*)d_in[2];
  const float* adj  = (const float*)d_in[3];
  const float* gw   = (const float*)d_in[4];
  const float* gb   = (const float*)d_in[5];
  const float* tw1  = (const float*)d_in[6];
  const float* tb1  = (const float*)d_in[7];
  const float* tw2  = (const float*)d_in[8];
  const float* tb2  = (const float*)d_in[9];
  const float* wq   = (const float*)d_in[10];
  const float* wk   = (const float*)d_in[11];
  const float* wv   = (const float*)d_in[12];
  const float* wo   = (const float*)d_in[13];
  const float* tg   = (const float*)d_in[14];
  const float* tbb  = (const float*)d_in[15];
  float* outp = (float*)d_out;

  char* p = (char*)d_ws;
  unsigned short* Sb  = (unsigned short*)p; p += 1048576;
  unsigned short* W8  = (unsigned short*)p; p += 9437184;
  float* biasn        = (float*)p;          p += 196608;
  unsigned short* G   = (unsigned short*)p; p += 33554432;
  unsigned short* H8a = (unsigned short*)p; p += 16777216;
  unsigned short* H8b = (unsigned short*)p; p += 16777216;
  unsigned short* Hra = (unsigned short*)p; p += 16777216;
  unsigned short* Hrb = (unsigned short*)p; p += 16777216;
  unsigned short* Wt  = (unsigned short*)p; p += 36864;
  unsigned short* Wf  = (unsigned short*)p; p += 16384;  // ~111.4 MB total

  prep_all<<<dim3(2166), dim3(256), 0, stream>>>(
      adj, Sb, emb, gw, gb, W8, biasn, tw1, tw2, Wt, wq, wk, wv, wo, Wf,
      x, H8a, Hra);

  gcn_phaseA<<<dim3(512), dim3(512), 0, stream>>>(Sb, H8a, G);
  gcn_phaseB<<<dim3(1024), dim3(256), 0, stream>>>(
      Hra, G, W8, biasn, H8b, Hrb);
  gcn_phaseA<<<dim3(512), dim3(512), 0, stream>>>(Sb, H8b, G);
  gcn_phaseB<<<dim3(1024), dim3(256), 0, stream>>>(
      Hrb, G, W8 + 1572864, biasn + 16384, H8a, Hra);
  gcn_phaseA<<<dim3(512), dim3(512), 0, stream>>>(Sb, H8a, G);
  // layer-3 weight apply fused with the full TCN stack; writes attn input
  gcn_phaseB_tcn<<<dim3(1024), dim3(256), 0, stream>>>(
      Hra, G, W8 + 3145728, biasn + 32768, Wt, tb1, tb2, H8b);

  attn_kernel<<<dim3(2048), dim3(512), 0, stream>>>(H8b, outp, Wf, tg, tbb);
}